// Round 8
// baseline (206.027 us; speedup 1.0000x reference)
//
#include <hip/hip_runtime.h>
#include <math.h>

// ---------------- problem constants ----------------
constexpr int BATCH  = 2;
constexpr int CDIM   = 96;    // model dim
constexpr int HH     = 56;
constexpr int WW     = 56;
constexpr int LL     = HH * WW;          // 3136
constexpr int DIN    = 192;              // d_inner
constexpr int NK     = 4;                // directions
constexpr int NST    = 16;               // d_state
constexpr int RNK    = 6;                // dt_rank
constexpr int EPROJ  = RNK + 2 * NST;    // 38
constexpr int SCH    = 64;               // steps per scan chunk
constexpr int NCH    = LL / SCH;         // 49 chunks
constexpr int CGRP   = DIN / 16;         // 12 channel-groups of 16 (scanA)
constexpr int C_DPB  = 32;               // d per block in scanC
constexpr int C_NBLK = DIN / C_DPB;      // 6 scanC blocks per (k,b)

// LDS strides (derived for 16B alignment + <=2-way banks)
constexpr int STDU = SCH + 2;   // float2 rows, stride 66
constexpr int STB1 = SCH + 4;   // float  rows, stride 68

// workspace layout (floats)
constexpr size_t SZ_PX   = (size_t)BATCH * LL * DIN;        // 1,204,224
constexpr size_t OFF_XP  = 0;
constexpr size_t OFF_Z   = OFF_XP + SZ_PX;
constexpr size_t OFF_XI  = OFF_Z  + SZ_PX;
constexpr size_t OFF_DR  = OFF_XI + SZ_PX;                  // dr: [kb][L][8]
constexpr size_t SZ_DR   = (size_t)NK * BATCH * LL * 8;
constexpr size_t OFF_B   = OFF_DR + SZ_DR;                  // B: K*B*L*16
constexpr size_t SZ_BC   = (size_t)NK * BATCH * LL * NST;
constexpr size_t OFF_C   = OFF_B + SZ_BC;
constexpr size_t OFF_YD  = OFF_C + SZ_BC;                   // ydir: [k][b][sp][d]
constexpr size_t SZ_YD   = (size_t)NK * BATCH * LL * DIN;   // 4,816,896
constexpr size_t OFF_HE  = OFF_YD + SZ_YD;                  // (P, h_end) float2 per chunk
constexpr size_t SZ_HS   = (size_t)NK * BATCH * NCH * DIN * NST;
constexpr size_t OFF_WT  = OFF_HE + 2 * SZ_HS;              // Wt: [k][e][d]
constexpr size_t SZ_WT   = (size_t)NK * EPROJ * DIN;        // 29,184

__device__ __forceinline__ float silu(float v) {
    return v / (1.0f + __expf(-v));
}

__device__ __forceinline__ float softplus_f(float x) {
    return (x > 20.0f) ? x : __logf(1.0f + __expf(x));
}

// direction k, sequence position l -> row-major spatial index
__device__ __forceinline__ int seq_to_lr(int k, int l) {
    int q = l / WW;
    int r = l - q * WW;
    if (k == 0) return l;
    if (k == 1) return q * WW + (WW - 1 - r);
    if (k == 2) return r * WW + q;
    return (WW - 1 - r) * WW + q;
}

// direction k, row-major spatial index s -> sequence position (inverse map)
__device__ __forceinline__ int spatial_to_seq(int k, int s) {
    int h = s / WW;
    int w = s - h * WW;
    if (k == 0) return s;
    if (k == 1) return h * WW + (WW - 1 - w);
    if (k == 2) return w * WW + h;
    return w * WW + (WW - 1 - h);
}

// chunk-summary index: [c][kb][d][n]
__device__ __forceinline__ size_t hs_idx(int c, int kb, int d, int n) {
    return ((size_t)(c * (NK * BATCH) + kb) * DIN + d) * NST + n;
}

// rank-6 delta: vectorized over 4 consecutive d (components of float4)
__device__ __forceinline__ float4 delta4(
        float4 r03, float2 r45, const float4* wr, float4 bb4) {
    float4 raw = bb4;
    raw.x = fmaf(r03.x, wr[0].x, raw.x); raw.y = fmaf(r03.x, wr[0].y, raw.y);
    raw.z = fmaf(r03.x, wr[0].z, raw.z); raw.w = fmaf(r03.x, wr[0].w, raw.w);
    raw.x = fmaf(r03.y, wr[1].x, raw.x); raw.y = fmaf(r03.y, wr[1].y, raw.y);
    raw.z = fmaf(r03.y, wr[1].z, raw.z); raw.w = fmaf(r03.y, wr[1].w, raw.w);
    raw.x = fmaf(r03.z, wr[2].x, raw.x); raw.y = fmaf(r03.z, wr[2].y, raw.y);
    raw.z = fmaf(r03.z, wr[2].z, raw.z); raw.w = fmaf(r03.z, wr[2].w, raw.w);
    raw.x = fmaf(r03.w, wr[3].x, raw.x); raw.y = fmaf(r03.w, wr[3].y, raw.y);
    raw.z = fmaf(r03.w, wr[3].z, raw.z); raw.w = fmaf(r03.w, wr[3].w, raw.w);
    raw.x = fmaf(r45.x, wr[4].x, raw.x); raw.y = fmaf(r45.x, wr[4].y, raw.y);
    raw.z = fmaf(r45.x, wr[4].z, raw.z); raw.w = fmaf(r45.x, wr[4].w, raw.w);
    raw.x = fmaf(r45.y, wr[5].x, raw.x); raw.y = fmaf(r45.y, wr[5].y, raw.y);
    raw.z = fmaf(r45.y, wr[5].z, raw.z); raw.w = fmaf(r45.y, wr[5].w, raw.w);
    raw.x = softplus_f(raw.x); raw.y = softplus_f(raw.y);
    raw.z = softplus_f(raw.z); raw.w = softplus_f(raw.w);
    return raw;
}

// ---------------- kernel 1: in-projection (x^T @ W_in -> xp, z) --------------
// Side job: first threads also transpose W_xproj -> Wt[k][e][d].
constexpr int K1_PIX = 8;
__global__ __launch_bounds__(384) void k_inproj(
        const float* __restrict__ x, const float* __restrict__ W_in,
        const float* __restrict__ W_xproj,
        float* __restrict__ xp, float* __restrict__ z, float* __restrict__ Wt) {
    __shared__ float sxT[CDIM][K1_PIX];   // [c][p], 3 KB
    int gp0 = blockIdx.x * K1_PIX;      // global pixel = b*LL + l
    int t   = threadIdx.x;
    int b   = gp0 / LL;
    int l0  = gp0 - b * LL;
    int gid = blockIdx.x * 384 + t;
    if (gid < NK * DIN * EPROJ) {
        int k = gid / (DIN * EPROJ);
        int r = gid % (DIN * EPROJ);
        int d = r / EPROJ;
        int e = r % EPROJ;
        Wt[((size_t)k * EPROJ + e) * DIN + d] = W_xproj[gid];
    }
    for (int i = t; i < CDIM * K1_PIX; i += 384) {
        int c = i >> 3, p = i & 7;
        sxT[c][p] = x[((size_t)(b * CDIM + c)) * LL + l0 + p];
    }
    __syncthreads();
    int e = t;                          // 0..383 output feature
    float acc[K1_PIX];
#pragma unroll
    for (int p = 0; p < K1_PIX; p++) acc[p] = 0.0f;
    const float4* sx4 = (const float4*)sxT;
#pragma unroll 4
    for (int c = 0; c < CDIM; c++) {
        float w  = W_in[c * (2 * DIN) + e];
        float4 va = sx4[2 * c];
        float4 vb = sx4[2 * c + 1];
        acc[0] = fmaf(va.x, w, acc[0]); acc[1] = fmaf(va.y, w, acc[1]);
        acc[2] = fmaf(va.z, w, acc[2]); acc[3] = fmaf(va.w, w, acc[3]);
        acc[4] = fmaf(vb.x, w, acc[4]); acc[5] = fmaf(vb.y, w, acc[5]);
        acc[6] = fmaf(vb.z, w, acc[6]); acc[7] = fmaf(vb.w, w, acc[7]);
    }
    if (e < DIN) {
#pragma unroll
        for (int p = 0; p < K1_PIX; p++)
            xp[((size_t)(gp0 + p)) * DIN + e] = acc[p];
    } else {
        int e2 = e - DIN;
#pragma unroll
        for (int p = 0; p < K1_PIX; p++)
            z[((size_t)(gp0 + p)) * DIN + e2] = acc[p];
    }
}

// ---------------- kernel 2: depthwise conv 3x3 + bias + SiLU ----------------
constexpr int KC_PIX = 4;
__global__ __launch_bounds__(192) void k_conv(
        const float* __restrict__ xp, const float* __restrict__ Wc,
        const float* __restrict__ bc, float* __restrict__ xi) {
    __shared__ float sW[9][DIN];          // 6.9 KB, transposed weights
    int t = threadIdx.x;
    for (int i = t; i < DIN * 9; i += 192) {
        int d = i / 9, tap = i % 9;
        sW[tap][d] = Wc[i];
    }
    __syncthreads();
    int p   = t / 48;            // pixel within block 0..3
    int cg4 = (t % 48) * 4;      // channel quad
    int gp  = blockIdx.x * KC_PIX + p;
    int b   = gp / LL;
    int l   = gp - b * LL;
    int h   = l / WW;
    int w   = l - h * WW;
    float4 acc = *(const float4*)&bc[cg4];
#pragma unroll
    for (int dy = -1; dy <= 1; dy++) {
        int hh = h + dy;
        if (hh < 0 || hh >= HH) continue;
#pragma unroll
        for (int dx = -1; dx <= 1; dx++) {
            int ww = w + dx;
            if (ww < 0 || ww >= WW) continue;
            float4 xv = *(const float4*)&xp[((size_t)b * LL + hh * WW + ww) * DIN + cg4];
            float4 wv = *(const float4*)&sW[(dy + 1) * 3 + (dx + 1)][cg4];
            acc.x = fmaf(xv.x, wv.x, acc.x);
            acc.y = fmaf(xv.y, wv.y, acc.y);
            acc.z = fmaf(xv.z, wv.z, acc.z);
            acc.w = fmaf(xv.w, wv.w, acc.w);
        }
    }
    float4 o;
    o.x = silu(acc.x); o.y = silu(acc.y); o.z = silu(acc.z); o.w = silu(acc.w);
    *(float4*)&xi[(size_t)gp * DIN + cg4] = o;
}

// ------- kernel 3: x-proj -> dr (rank-6), B, C ------------------------------
constexpr int K3_PIX = 32;
__global__ __launch_bounds__(256) void k_xproj(
        const float* __restrict__ xi, const float* __restrict__ Wt,
        float* __restrict__ drbuf, float* __restrict__ Bbuf,
        float* __restrict__ Cbuf) {
    __shared__ float4 v4[K3_PIX][49];    // 25.1 KB
    int k   = blockIdx.y;
    int gp0 = blockIdx.x * K3_PIX;
    int b   = gp0 / LL;
    int l0  = gp0 - b * LL;
    int t   = threadIdx.x;
    const float4* xin4 = (const float4*)(xi + (size_t)gp0 * DIN);
    for (int i = t; i < K3_PIX * 48; i += 256)
        v4[i / 48][i % 48] = xin4[i];
    const float4* wt4 = (const float4*)(Wt + (size_t)k * EPROJ * DIN);
    __syncthreads();
    int p0 = t & 15;            // pixel within 16-set
    int eg = t >> 4;            // e-group 0..15
    bool has3 = (eg < EPROJ - 32);      // eg < 6
    float acc[2][3] = {{0.f, 0.f, 0.f}, {0.f, 0.f, 0.f}};
#pragma unroll 4
    for (int j = 0; j < 48; j++) {
        float4 w0 = wt4[eg * 48 + j];
        float4 w1 = wt4[(eg + 16) * 48 + j];
        float4 w2 = has3 ? wt4[(eg + 32) * 48 + j] : make_float4(0.f, 0.f, 0.f, 0.f);
#pragma unroll
        for (int q = 0; q < 2; q++) {
            float4 vv = v4[p0 + 16 * q][j];
            acc[q][0] = fmaf(vv.x, w0.x, acc[q][0]); acc[q][0] = fmaf(vv.y, w0.y, acc[q][0]);
            acc[q][0] = fmaf(vv.z, w0.z, acc[q][0]); acc[q][0] = fmaf(vv.w, w0.w, acc[q][0]);
            acc[q][1] = fmaf(vv.x, w1.x, acc[q][1]); acc[q][1] = fmaf(vv.y, w1.y, acc[q][1]);
            acc[q][1] = fmaf(vv.z, w1.z, acc[q][1]); acc[q][1] = fmaf(vv.w, w1.w, acc[q][1]);
            acc[q][2] = fmaf(vv.x, w2.x, acc[q][2]); acc[q][2] = fmaf(vv.y, w2.y, acc[q][2]);
            acc[q][2] = fmaf(vv.z, w2.z, acc[q][2]); acc[q][2] = fmaf(vv.w, w2.w, acc[q][2]);
        }
    }
#pragma unroll
    for (int q = 0; q < 2; q++) {
        int p  = p0 + 16 * q;
        int ls = spatial_to_seq(k, l0 + p);
        size_t kb  = (size_t)(k * BATCH + b);
        size_t b8  = (kb * LL + ls) * 8;
        size_t b16 = (kb * LL + ls) * NST;
        if (eg < RNK) drbuf[b8 + eg] = acc[q][0];
        else          Bbuf[b16 + eg - RNK] = acc[q][0];
        int e1 = eg + 16;
        if (e1 < RNK + NST) Bbuf[b16 + e1 - RNK] = acc[q][1];
        else                Cbuf[b16 + e1 - RNK - NST] = acc[q][1];
        if (has3) Cbuf[b16 + eg + 32 - RNK - NST] = acc[q][2];
    }
}

// -------- kernel 4a: chunk summary (P, h_end) — parallel suffix-sum form ----
// (unchanged from R7 — passed with identical absmax)
__global__ __launch_bounds__(256) void k_scanA(
        const float* __restrict__ xi, const float* __restrict__ drbuf,
        const float* __restrict__ Bbuf, const float* __restrict__ A_logs,
        const float* __restrict__ W_dt, const float* __restrict__ b_dt,
        float2* __restrict__ sum2) {
    __shared__ float2 sDU2[16][STDU];   // [ch][s] {delta, delta*u}
    __shared__ float  sB1t[16][STB1];   // [n][s]
    __shared__ float  sT[16][68];       // [ch][j]: T_j, j=0..63; [64] = total
    int c   = blockIdx.x;
    int blk = blockIdx.y;
    int k   = blk / (BATCH * CGRP);
    int rem = blk % (BATCH * CGRP);
    int b   = rem / CGRP;
    int cg  = rem % CGRP;
    int d0  = cg * 16;
    int t    = threadIdx.x;
    int lane = t & 63, wave = t >> 6;
    int grp  = lane >> 4, n = lane & 15;
    int ch   = wave * 4 + grp;
    int d    = d0 + ch;
    float A = -__expf(A_logs[((size_t)(k * DIN + d)) * NST + n]);
    size_t kb = (size_t)(k * BATCH + b);
    const float* drp = drbuf + kb * LL * 8;
    const float* bp  = Bbuf  + kb * LL * NST;
    const float* up  = xi    + (size_t)b * LL * DIN;
    int ss  = t >> 2;            // 0..63
    int cc0 = (t & 3) * 4;       // 0,4,8,12
    float4 wr[RNK];
#pragma unroll
    for (int r = 0; r < RNK; r++)
        wr[r] = *(const float4*)(W_dt + ((size_t)k * RNK + r) * DIN + d0 + cc0);
    float4 bb4 = *(const float4*)(b_dt + k * DIN + d0 + cc0);
    int l0 = c * SCH;
    {
        int l  = l0 + ss;
        int lr = seq_to_lr(k, l);
        float4 r03 = *(const float4*)(drp + (size_t)l * 8);
        float2 r45 = *(const float2*)(drp + (size_t)l * 8 + 4);
        float4 dlt = delta4(r03, r45, wr, bb4);
        float4 u4  = *(const float4*)(up + (size_t)lr * DIN + d0 + cc0);
        float4 B4  = *(const float4*)(bp + (size_t)l * NST + cc0);
        sDU2[cc0 + 0][ss] = make_float2(dlt.x, dlt.x * u4.x);
        sDU2[cc0 + 1][ss] = make_float2(dlt.y, dlt.y * u4.y);
        sDU2[cc0 + 2][ss] = make_float2(dlt.z, dlt.z * u4.z);
        sDU2[cc0 + 3][ss] = make_float2(dlt.w, dlt.w * u4.w);
        sB1t[cc0 + 0][ss] = B4.x;
        sB1t[cc0 + 1][ss] = B4.y;
        sB1t[cc0 + 2][ss] = B4.z;
        sB1t[cc0 + 3][ss] = B4.w;
    }
    __syncthreads();
    if (t < 16) {
        float run = 0.0f;
#pragma unroll 8
        for (int j = SCH - 1; j >= 0; j--) {
            sT[t][j] = run;
            run += sDU2[t][j].x;
        }
        sT[t][SCH] = run;        // total sum of deltas
    }
    __syncthreads();
    float h0 = 0.f, h1 = 0.f, h2 = 0.f, h3 = 0.f;
#pragma unroll 2
    for (int j = 0; j < SCH; j += 4) {
        float4 tq  = *(const float4*)&sT[ch][j];          // T_j .. T_j+3
        float4 duA = *(const float4*)&sDU2[ch][j];        // {d,du,d,du}
        float4 duB = *(const float4*)&sDU2[ch][j + 2];
        float4 bq  = *(const float4*)&sB1t[n][j];
        h0 = fmaf(__expf(A * tq.x), duA.y * bq.x, h0);
        h1 = fmaf(__expf(A * tq.y), duA.w * bq.y, h1);
        h2 = fmaf(__expf(A * tq.z), duB.y * bq.z, h2);
        h3 = fmaf(__expf(A * tq.w), duB.w * bq.w, h3);
    }
    float h = (h0 + h1) + (h2 + h3);
    float P = __expf(A * sT[ch][SCH]);
    sum2[hs_idx(c, (int)kb, d, n)] = make_float2(P, h);
}

// -------- kernel 4b: chunk scan, 4-states-per-lane + quad-DPP reduce ---------
// Lane = (d_local = lane>>2 within wave, ng = lane&3); each lane owns 4
// states n = ng*4..+3 as 4 independent h chains (ILP). y = quad dot (1 mul +
// 3 fma) + 2 quad_perm DPP adds across the 4 lanes of a d. Replaces the
// 16-lane DPP tree (8 ops x 16 lanes): per (d,step) 208 -> ~80 lane-ops.
// LDS patterns bank-verified: sDU2[d][s] b64 = distinct even-bank pairs,
// sB4/sC4[s][ng] = 4 addrs x 16-lane broadcast. 34.4 KB -> 4 blocks/CU.
__global__ __launch_bounds__(128) void k_scanC(
        const float* __restrict__ xi, const float* __restrict__ drbuf,
        const float* __restrict__ Bbuf, const float* __restrict__ Cbuf,
        const float* __restrict__ A_logs, const float* __restrict__ W_dt,
        const float* __restrict__ b_dt,
        const float2* __restrict__ sum2,
        float* __restrict__ ydir) {
    __shared__ float2 sDU2[C_DPB][65];   // [d][s] {delta, delta*u}
    __shared__ float4 sB4[SCH][5];       // [s][ng] = B[s][ng*4..+3]
    __shared__ float4 sC4[SCH][5];       // [s][ng]
    __shared__ float  sY[C_DPB][65];     // [d][s]
    int c   = blockIdx.x;
    int blk = blockIdx.y;
    int k   = blk / (BATCH * C_NBLK);
    int rem = blk % (BATCH * C_NBLK);
    int b   = rem / C_NBLK;
    int g   = rem % C_NBLK;
    int d0  = g * C_DPB;
    int t    = threadIdx.x;
    int lane = t & 63, wave = t >> 6;
    int dl   = wave * 16 + (lane >> 2);  // d_local 0..31
    int ng   = lane & 3;
    int n0   = ng * 4;
    int d    = d0 + dl;
    size_t kb = (size_t)(k * BATCH + b);
    const float* drp = drbuf + kb * LL * 8;
    const float* bp  = Bbuf  + kb * LL * NST;
    const float* cp  = Cbuf  + kb * LL * NST;
    const float* up  = xi    + (size_t)b * LL * DIN;
    float*       yp  = ydir  + kb * LL * DIN;     // per-direction slice
    // A for this lane's 4 states
    float4 al = *(const float4*)(A_logs + ((size_t)(k * DIN + d)) * NST + n0);
    float A0 = -__expf(al.x), A1 = -__expf(al.y);
    float A2 = -__expf(al.z), A3 = -__expf(al.w);
    // ---- inline prefix fold: h_in for 4 states (float4-paired loads) ----
    float h0 = 0.f, h1 = 0.f, h2 = 0.f, h3 = 0.f;
    {
        int j = 0;
        for (; j + 4 <= c; j += 4) {
            const float4* p0 = (const float4*)(sum2 + hs_idx(j + 0, (int)kb, d, n0));
            const float4* p1 = (const float4*)(sum2 + hs_idx(j + 1, (int)kb, d, n0));
            const float4* p2 = (const float4*)(sum2 + hs_idx(j + 2, (int)kb, d, n0));
            const float4* p3 = (const float4*)(sum2 + hs_idx(j + 3, (int)kb, d, n0));
            float4 a0 = p0[0], b0 = p0[1];
            float4 a1 = p1[0], b1 = p1[1];
            float4 a2 = p2[0], b2 = p2[1];
            float4 a3 = p3[0], b3 = p3[1];
            h0 = fmaf(a0.x, h0, a0.y); h1 = fmaf(a0.z, h1, a0.w);
            h2 = fmaf(b0.x, h2, b0.y); h3 = fmaf(b0.z, h3, b0.w);
            h0 = fmaf(a1.x, h0, a1.y); h1 = fmaf(a1.z, h1, a1.w);
            h2 = fmaf(b1.x, h2, b1.y); h3 = fmaf(b1.z, h3, b1.w);
            h0 = fmaf(a2.x, h0, a2.y); h1 = fmaf(a2.z, h1, a2.w);
            h2 = fmaf(b2.x, h2, b2.y); h3 = fmaf(b2.z, h3, b2.w);
            h0 = fmaf(a3.x, h0, a3.y); h1 = fmaf(a3.z, h1, a3.w);
            h2 = fmaf(b3.x, h2, b3.y); h3 = fmaf(b3.z, h3, b3.w);
        }
        for (; j < c; j++) {
            const float4* pj = (const float4*)(sum2 + hs_idx(j, (int)kb, d, n0));
            float4 a = pj[0], bq = pj[1];
            h0 = fmaf(a.x, h0, a.y); h1 = fmaf(a.z, h1, a.w);
            h2 = fmaf(bq.x, h2, bq.y); h3 = fmaf(bq.z, h3, bq.w);
        }
    }
    // ---- stage chunk data (128 threads: s = t&63, dgroup = t>>6) ----
    int l0 = c * SCH;
    {
        int ss = t & 63;
        int dg = t >> 6;             // 0..1 -> d range [dg*16, dg*16+16)
        int l  = l0 + ss;
        int lr = seq_to_lr(k, l);
        float4 r03 = *(const float4*)(drp + (size_t)l * 8);
        float2 r45 = *(const float2*)(drp + (size_t)l * 8 + 4);
#pragma unroll
        for (int q = 0; q < 4; q++) {
            int cc0 = dg * 16 + q * 4;
            float4 wr[RNK];
#pragma unroll
            for (int r = 0; r < RNK; r++)
                wr[r] = *(const float4*)(W_dt + ((size_t)k * RNK + r) * DIN + d0 + cc0);
            float4 bb4 = *(const float4*)(b_dt + k * DIN + d0 + cc0);
            float4 dlt = delta4(r03, r45, wr, bb4);
            float4 u4  = *(const float4*)(up + (size_t)lr * DIN + d0 + cc0);
            sDU2[cc0 + 0][ss] = make_float2(dlt.x, dlt.x * u4.x);
            sDU2[cc0 + 1][ss] = make_float2(dlt.y, dlt.y * u4.y);
            sDU2[cc0 + 2][ss] = make_float2(dlt.z, dlt.z * u4.z);
            sDU2[cc0 + 3][ss] = make_float2(dlt.w, dlt.w * u4.w);
        }
        // B / C quads: first wave stages B, second stages C
        int s2 = t & 63;
        int l2 = l0 + s2;
        if (t < 64) {
#pragma unroll
            for (int q = 0; q < 4; q++)
                sB4[s2][q] = *(const float4*)(bp + (size_t)l2 * NST + q * 4);
        } else {
#pragma unroll
            for (int q = 0; q < 4; q++)
                sC4[s2][q] = *(const float4*)(cp + (size_t)l2 * NST + q * 4);
        }
    }
    __syncthreads();
    // ---- main scan: 4 independent h chains per lane, quad reduce ----
#pragma unroll 4
    for (int s = 0; s < SCH; s++) {
        float2 du = sDU2[dl][s];
        float4 B4 = sB4[s][ng];
        float4 C4 = sC4[s][ng];
        h0 = fmaf(__expf(du.x * A0), h0, du.y * B4.x);
        h1 = fmaf(__expf(du.x * A1), h1, du.y * B4.y);
        h2 = fmaf(__expf(du.x * A2), h2, du.y * B4.z);
        h3 = fmaf(__expf(du.x * A3), h3, du.y * B4.w);
        float yq = (h0 * C4.x + h1 * C4.y) + (h2 * C4.z + h3 * C4.w);
        yq += __int_as_float(__builtin_amdgcn_update_dpp(
                0, __float_as_int(yq), 0xB1, 0xf, 0xf, true));  // quad_perm 1,0,3,2
        yq += __int_as_float(__builtin_amdgcn_update_dpp(
                0, __float_as_int(yq), 0x4E, 0xf, 0xf, true));  // quad_perm 2,3,0,1
        if (ng == 0) sY[dl][s] = yq;
    }
    __syncthreads();
    // ---- writeback: float4 over d, coalesced over s ----
    for (int i = t; i < SCH * (C_DPB / 4); i += 128) {
        int dq = i & (C_DPB / 4 - 1);    // 0..7
        int s  = i >> 3;
        int lr = seq_to_lr(k, l0 + s);
        float4 v = make_float4(sY[dq * 4 + 0][s], sY[dq * 4 + 1][s],
                               sY[dq * 4 + 2][s], sY[dq * 4 + 3][s]);
        *(float4*)&yp[(size_t)lr * DIN + d0 + dq * 4] = v;
    }
}

// ------- kernel 5: gather 4 directions + D*u + gate + out-projection ---------
constexpr int K5_PIX = 8;
__global__ __launch_bounds__(192) void k_out(
        const float* __restrict__ ydir, const float* __restrict__ xi,
        const float* __restrict__ zbuf, const float* __restrict__ Ds,
        const float* __restrict__ W_out, float* __restrict__ out) {
    __shared__ float g[DIN][12];           // [dd][p] padded
    __shared__ float so[CDIM][9];          // padded stores
    int gp0 = blockIdx.x * K5_PIX;
    int b   = gp0 / LL;
    int l0  = gp0 - b * LL;
    int t   = threadIdx.x;
    for (int i = t; i < K5_PIX * DIN; i += 192) {
        int p = i / DIN, dd = i % DIN;
        size_t off = (size_t)(gp0 + p) * DIN + dd;
        float y = ydir[off] + ydir[SZ_PX + off]
                + ydir[2 * SZ_PX + off] + ydir[3 * SZ_PX + off];
        float dsum = Ds[dd] + Ds[DIN + dd] + Ds[2 * DIN + dd] + Ds[3 * DIN + dd];
        y = fmaf(xi[off], dsum, y);
        g[dd][p] = y * silu(zbuf[off]);
    }
    __syncthreads();
    int f    = t % CDIM;
    int half = t / CDIM;
    float acc[4] = {0.f, 0.f, 0.f, 0.f};
#pragma unroll 4
    for (int dd = 0; dd < DIN; dd++) {
        float wv = W_out[dd * CDIM + f];
        float4 gv = *(const float4*)&g[dd][half * 4];
        acc[0] = fmaf(gv.x, wv, acc[0]);
        acc[1] = fmaf(gv.y, wv, acc[1]);
        acc[2] = fmaf(gv.z, wv, acc[2]);
        acc[3] = fmaf(gv.w, wv, acc[3]);
    }
#pragma unroll
    for (int p = 0; p < 4; p++) so[f][half * 4 + p] = acc[p];
    __syncthreads();
    for (int i = t; i < CDIM * K5_PIX; i += 192) {
        int f2 = i / K5_PIX, p2 = i % K5_PIX;
        out[((size_t)(b * CDIM + f2)) * LL + l0 + p2] = so[f2][p2];
    }
}

// ---------------- launch ----------------------------------------------------
extern "C" void kernel_launch(void* const* d_in, const int* in_sizes, int n_in,
                              void* d_out, int out_size, void* d_ws, size_t ws_size,
                              hipStream_t stream) {
    const float* x       = (const float*)d_in[0];
    const float* W_in    = (const float*)d_in[1];
    const float* W_conv  = (const float*)d_in[2];
    const float* b_conv  = (const float*)d_in[3];
    const float* W_xproj = (const float*)d_in[4];
    const float* W_dt    = (const float*)d_in[5];
    const float* b_dt    = (const float*)d_in[6];
    const float* A_logs  = (const float*)d_in[7];
    const float* Ds      = (const float*)d_in[8];
    const float* W_out   = (const float*)d_in[9];
    float* out = (float*)d_out;
    float* ws  = (float*)d_ws;

    float* xp    = ws + OFF_XP;
    float* z     = ws + OFF_Z;
    float* xi    = ws + OFF_XI;
    float* drbuf = ws + OFF_DR;
    float* Bbuf  = ws + OFF_B;
    float* Cbuf  = ws + OFF_C;
    float* ydir  = ws + OFF_YD;
    float2* sum2 = (float2*)(ws + OFF_HE);
    float* Wt    = ws + OFF_WT;

    k_inproj<<<(BATCH * LL) / K1_PIX, 384, 0, stream>>>(x, W_in, W_xproj, xp, z, Wt);
    k_conv<<<(BATCH * LL) / KC_PIX, 192, 0, stream>>>(xp, W_conv, b_conv, xi);
    dim3 g3((BATCH * LL) / K3_PIX, NK);
    k_xproj<<<g3, 256, 0, stream>>>(xi, Wt, drbuf, Bbuf, Cbuf);
    dim3 gsA(NCH, NK * BATCH * CGRP);
    k_scanA<<<gsA, 256, 0, stream>>>(xi, drbuf, Bbuf, A_logs, W_dt, b_dt, sum2);
    dim3 gsC(NCH, NK * BATCH * C_NBLK);
    k_scanC<<<gsC, 128, 0, stream>>>(xi, drbuf, Bbuf, Cbuf, A_logs, W_dt, b_dt, sum2, ydir);
    k_out<<<(BATCH * LL) / K5_PIX, 192, 0, stream>>>(ydir, xi, z, Ds, W_out, out);
}

// Round 9
// 204.052 us; speedup vs baseline: 1.0097x; 1.0097x over previous
//
#include <hip/hip_runtime.h>
#include <math.h>

// ---------------- problem constants ----------------
constexpr int BATCH  = 2;
constexpr int CDIM   = 96;    // model dim
constexpr int HH     = 56;
constexpr int WW     = 56;
constexpr int LL     = HH * WW;          // 3136
constexpr int DIN    = 192;              // d_inner
constexpr int NK     = 4;                // directions
constexpr int NST    = 16;               // d_state
constexpr int RNK    = 6;                // dt_rank
constexpr int EPROJ  = RNK + 2 * NST;    // 38
constexpr int SCH    = 64;               // steps per scan chunk
constexpr int NCH    = LL / SCH;         // 49 chunks
constexpr int CGRP   = DIN / 16;         // 12 channel-groups of 16 (scanA)
constexpr int C_DPB  = 64;               // d per block in scanC
constexpr int C_NBLK = DIN / C_DPB;      // 3 scanC blocks per (k,b)

// LDS strides (derived for 16B alignment + <=2-way banks)
constexpr int STDU = SCH + 2;   // float2 rows, stride 66
constexpr int STB1 = SCH + 4;   // float  rows, stride 68

// workspace layout (floats)
constexpr size_t SZ_PX   = (size_t)BATCH * LL * DIN;        // 1,204,224
constexpr size_t OFF_XP  = 0;
constexpr size_t OFF_Z   = OFF_XP + SZ_PX;
constexpr size_t OFF_XI  = OFF_Z  + SZ_PX;
constexpr size_t OFF_DR  = OFF_XI + SZ_PX;                  // dr: [kb][L][8]
constexpr size_t SZ_DR   = (size_t)NK * BATCH * LL * 8;
constexpr size_t OFF_B   = OFF_DR + SZ_DR;                  // B: K*B*L*16
constexpr size_t SZ_BC   = (size_t)NK * BATCH * LL * NST;
constexpr size_t OFF_C   = OFF_B + SZ_BC;
constexpr size_t OFF_YD  = OFF_C + SZ_BC;                   // ydir: [k][b][sp][d]
constexpr size_t SZ_YD   = (size_t)NK * BATCH * LL * DIN;   // 4,816,896
constexpr size_t OFF_HE  = OFF_YD + SZ_YD;                  // (P, h_end) float2 per chunk
constexpr size_t SZ_HS   = (size_t)NK * BATCH * NCH * DIN * NST;
constexpr size_t OFF_WT  = OFF_HE + 2 * SZ_HS;              // Wt: [k][e][d]
constexpr size_t SZ_WT   = (size_t)NK * EPROJ * DIN;        // 29,184

__device__ __forceinline__ float silu(float v) {
    return v / (1.0f + __expf(-v));
}

__device__ __forceinline__ float softplus_f(float x) {
    return (x > 20.0f) ? x : __logf(1.0f + __expf(x));
}

// direction k, sequence position l -> row-major spatial index
__device__ __forceinline__ int seq_to_lr(int k, int l) {
    int q = l / WW;
    int r = l - q * WW;
    if (k == 0) return l;
    if (k == 1) return q * WW + (WW - 1 - r);
    if (k == 2) return r * WW + q;
    return (WW - 1 - r) * WW + q;
}

// direction k, row-major spatial index s -> sequence position (inverse map)
__device__ __forceinline__ int spatial_to_seq(int k, int s) {
    int h = s / WW;
    int w = s - h * WW;
    if (k == 0) return s;
    if (k == 1) return h * WW + (WW - 1 - w);
    if (k == 2) return w * WW + h;
    return w * WW + (WW - 1 - h);
}

// chunk-summary index: [c][kb][d][n]
__device__ __forceinline__ size_t hs_idx(int c, int kb, int d, int n) {
    return ((size_t)(c * (NK * BATCH) + kb) * DIN + d) * NST + n;
}

// rank-6 delta: vectorized over 4 consecutive d (components of float4)
__device__ __forceinline__ float4 delta4(
        float4 r03, float2 r45, const float4* wr, float4 bb4) {
    float4 raw = bb4;
    raw.x = fmaf(r03.x, wr[0].x, raw.x); raw.y = fmaf(r03.x, wr[0].y, raw.y);
    raw.z = fmaf(r03.x, wr[0].z, raw.z); raw.w = fmaf(r03.x, wr[0].w, raw.w);
    raw.x = fmaf(r03.y, wr[1].x, raw.x); raw.y = fmaf(r03.y, wr[1].y, raw.y);
    raw.z = fmaf(r03.y, wr[1].z, raw.z); raw.w = fmaf(r03.y, wr[1].w, raw.w);
    raw.x = fmaf(r03.z, wr[2].x, raw.x); raw.y = fmaf(r03.z, wr[2].y, raw.y);
    raw.z = fmaf(r03.z, wr[2].z, raw.z); raw.w = fmaf(r03.z, wr[2].w, raw.w);
    raw.x = fmaf(r03.w, wr[3].x, raw.x); raw.y = fmaf(r03.w, wr[3].y, raw.y);
    raw.z = fmaf(r03.w, wr[3].z, raw.z); raw.w = fmaf(r03.w, wr[3].w, raw.w);
    raw.x = fmaf(r45.x, wr[4].x, raw.x); raw.y = fmaf(r45.x, wr[4].y, raw.y);
    raw.z = fmaf(r45.x, wr[4].z, raw.z); raw.w = fmaf(r45.x, wr[4].w, raw.w);
    raw.x = fmaf(r45.y, wr[5].x, raw.x); raw.y = fmaf(r45.y, wr[5].y, raw.y);
    raw.z = fmaf(r45.y, wr[5].z, raw.z); raw.w = fmaf(r45.y, wr[5].w, raw.w);
    raw.x = softplus_f(raw.x); raw.y = softplus_f(raw.y);
    raw.z = softplus_f(raw.z); raw.w = softplus_f(raw.w);
    return raw;
}

// ---------------- kernel 1: in-projection (x^T @ W_in -> xp, z) --------------
// Side job: first threads also transpose W_xproj -> Wt[k][e][d].
constexpr int K1_PIX = 8;
__global__ __launch_bounds__(384) void k_inproj(
        const float* __restrict__ x, const float* __restrict__ W_in,
        const float* __restrict__ W_xproj,
        float* __restrict__ xp, float* __restrict__ z, float* __restrict__ Wt) {
    __shared__ float sxT[CDIM][K1_PIX];   // [c][p], 3 KB
    int gp0 = blockIdx.x * K1_PIX;      // global pixel = b*LL + l
    int t   = threadIdx.x;
    int b   = gp0 / LL;
    int l0  = gp0 - b * LL;
    int gid = blockIdx.x * 384 + t;
    if (gid < NK * DIN * EPROJ) {
        int k = gid / (DIN * EPROJ);
        int r = gid % (DIN * EPROJ);
        int d = r / EPROJ;
        int e = r % EPROJ;
        Wt[((size_t)k * EPROJ + e) * DIN + d] = W_xproj[gid];
    }
    for (int i = t; i < CDIM * K1_PIX; i += 384) {
        int c = i >> 3, p = i & 7;
        sxT[c][p] = x[((size_t)(b * CDIM + c)) * LL + l0 + p];
    }
    __syncthreads();
    int e = t;                          // 0..383 output feature
    float acc[K1_PIX];
#pragma unroll
    for (int p = 0; p < K1_PIX; p++) acc[p] = 0.0f;
    const float4* sx4 = (const float4*)sxT;
#pragma unroll 4
    for (int c = 0; c < CDIM; c++) {
        float w  = W_in[c * (2 * DIN) + e];
        float4 va = sx4[2 * c];
        float4 vb = sx4[2 * c + 1];
        acc[0] = fmaf(va.x, w, acc[0]); acc[1] = fmaf(va.y, w, acc[1]);
        acc[2] = fmaf(va.z, w, acc[2]); acc[3] = fmaf(va.w, w, acc[3]);
        acc[4] = fmaf(vb.x, w, acc[4]); acc[5] = fmaf(vb.y, w, acc[5]);
        acc[6] = fmaf(vb.z, w, acc[6]); acc[7] = fmaf(vb.w, w, acc[7]);
    }
    if (e < DIN) {
#pragma unroll
        for (int p = 0; p < K1_PIX; p++)
            xp[((size_t)(gp0 + p)) * DIN + e] = acc[p];
    } else {
        int e2 = e - DIN;
#pragma unroll
        for (int p = 0; p < K1_PIX; p++)
            z[((size_t)(gp0 + p)) * DIN + e2] = acc[p];
    }
}

// ---------------- kernel 2: depthwise conv 3x3 + bias + SiLU ----------------
constexpr int KC_PIX = 4;
__global__ __launch_bounds__(192) void k_conv(
        const float* __restrict__ xp, const float* __restrict__ Wc,
        const float* __restrict__ bc, float* __restrict__ xi) {
    __shared__ float sW[9][DIN];          // 6.9 KB, transposed weights
    int t = threadIdx.x;
    for (int i = t; i < DIN * 9; i += 192) {
        int d = i / 9, tap = i % 9;
        sW[tap][d] = Wc[i];
    }
    __syncthreads();
    int p   = t / 48;            // pixel within block 0..3
    int cg4 = (t % 48) * 4;      // channel quad
    int gp  = blockIdx.x * KC_PIX + p;
    int b   = gp / LL;
    int l   = gp - b * LL;
    int h   = l / WW;
    int w   = l - h * WW;
    float4 acc = *(const float4*)&bc[cg4];
#pragma unroll
    for (int dy = -1; dy <= 1; dy++) {
        int hh = h + dy;
        if (hh < 0 || hh >= HH) continue;
#pragma unroll
        for (int dx = -1; dx <= 1; dx++) {
            int ww = w + dx;
            if (ww < 0 || ww >= WW) continue;
            float4 xv = *(const float4*)&xp[((size_t)b * LL + hh * WW + ww) * DIN + cg4];
            float4 wv = *(const float4*)&sW[(dy + 1) * 3 + (dx + 1)][cg4];
            acc.x = fmaf(xv.x, wv.x, acc.x);
            acc.y = fmaf(xv.y, wv.y, acc.y);
            acc.z = fmaf(xv.z, wv.z, acc.z);
            acc.w = fmaf(xv.w, wv.w, acc.w);
        }
    }
    float4 o;
    o.x = silu(acc.x); o.y = silu(acc.y); o.z = silu(acc.z); o.w = silu(acc.w);
    *(float4*)&xi[(size_t)gp * DIN + cg4] = o;
}

// ------- kernel 3: x-proj -> dr (rank-6), B, C ------------------------------
constexpr int K3_PIX = 32;
__global__ __launch_bounds__(256) void k_xproj(
        const float* __restrict__ xi, const float* __restrict__ Wt,
        float* __restrict__ drbuf, float* __restrict__ Bbuf,
        float* __restrict__ Cbuf) {
    __shared__ float4 v4[K3_PIX][49];    // 25.1 KB
    int k   = blockIdx.y;
    int gp0 = blockIdx.x * K3_PIX;
    int b   = gp0 / LL;
    int l0  = gp0 - b * LL;
    int t   = threadIdx.x;
    const float4* xin4 = (const float4*)(xi + (size_t)gp0 * DIN);
    for (int i = t; i < K3_PIX * 48; i += 256)
        v4[i / 48][i % 48] = xin4[i];
    const float4* wt4 = (const float4*)(Wt + (size_t)k * EPROJ * DIN);
    __syncthreads();
    int p0 = t & 15;            // pixel within 16-set
    int eg = t >> 4;            // e-group 0..15
    bool has3 = (eg < EPROJ - 32);      // eg < 6
    float acc[2][3] = {{0.f, 0.f, 0.f}, {0.f, 0.f, 0.f}};
#pragma unroll 4
    for (int j = 0; j < 48; j++) {
        float4 w0 = wt4[eg * 48 + j];
        float4 w1 = wt4[(eg + 16) * 48 + j];
        float4 w2 = has3 ? wt4[(eg + 32) * 48 + j] : make_float4(0.f, 0.f, 0.f, 0.f);
#pragma unroll
        for (int q = 0; q < 2; q++) {
            float4 vv = v4[p0 + 16 * q][j];
            acc[q][0] = fmaf(vv.x, w0.x, acc[q][0]); acc[q][0] = fmaf(vv.y, w0.y, acc[q][0]);
            acc[q][0] = fmaf(vv.z, w0.z, acc[q][0]); acc[q][0] = fmaf(vv.w, w0.w, acc[q][0]);
            acc[q][1] = fmaf(vv.x, w1.x, acc[q][1]); acc[q][1] = fmaf(vv.y, w1.y, acc[q][1]);
            acc[q][1] = fmaf(vv.z, w1.z, acc[q][1]); acc[q][1] = fmaf(vv.w, w1.w, acc[q][1]);
            acc[q][2] = fmaf(vv.x, w2.x, acc[q][2]); acc[q][2] = fmaf(vv.y, w2.y, acc[q][2]);
            acc[q][2] = fmaf(vv.z, w2.z, acc[q][2]); acc[q][2] = fmaf(vv.w, w2.w, acc[q][2]);
        }
    }
#pragma unroll
    for (int q = 0; q < 2; q++) {
        int p  = p0 + 16 * q;
        int ls = spatial_to_seq(k, l0 + p);
        size_t kb  = (size_t)(k * BATCH + b);
        size_t b8  = (kb * LL + ls) * 8;
        size_t b16 = (kb * LL + ls) * NST;
        if (eg < RNK) drbuf[b8 + eg] = acc[q][0];
        else          Bbuf[b16 + eg - RNK] = acc[q][0];
        int e1 = eg + 16;
        if (e1 < RNK + NST) Bbuf[b16 + e1 - RNK] = acc[q][1];
        else                Cbuf[b16 + e1 - RNK - NST] = acc[q][1];
        if (has3) Cbuf[b16 + eg + 32 - RNK - NST] = acc[q][2];
    }
}

// -------- kernel 4a: chunk-local scan -> (P, h_end) — R5-proven serial form --
__global__ __launch_bounds__(256) void k_scanA(
        const float* __restrict__ xi, const float* __restrict__ drbuf,
        const float* __restrict__ Bbuf, const float* __restrict__ A_logs,
        const float* __restrict__ W_dt, const float* __restrict__ b_dt,
        float2* __restrict__ sum2) {
    __shared__ float2 sDU2[16][STDU];   // [ch][s] {delta, delta*u}
    __shared__ float  sB1t[16][STB1];   // [n][s]
    int c   = blockIdx.x;
    int blk = blockIdx.y;
    int k   = blk / (BATCH * CGRP);
    int rem = blk % (BATCH * CGRP);
    int b   = rem / CGRP;
    int cg  = rem % CGRP;
    int d0  = cg * 16;
    int t    = threadIdx.x;
    int lane = t & 63, wave = t >> 6;
    int grp  = lane >> 4, n = lane & 15;
    int ch   = wave * 4 + grp;
    int d    = d0 + ch;
    float A = -__expf(A_logs[((size_t)(k * DIN + d)) * NST + n]);
    size_t kb = (size_t)(k * BATCH + b);
    const float* drp = drbuf + kb * LL * 8;
    const float* bp  = Bbuf  + kb * LL * NST;
    const float* up  = xi    + (size_t)b * LL * DIN;
    int ss  = t >> 2;            // 0..63
    int cc0 = (t & 3) * 4;       // 0,4,8,12
    float4 wr[RNK];
#pragma unroll
    for (int r = 0; r < RNK; r++)
        wr[r] = *(const float4*)(W_dt + ((size_t)k * RNK + r) * DIN + d0 + cc0);
    float4 bb4 = *(const float4*)(b_dt + k * DIN + d0 + cc0);
    int l0 = c * SCH;
    {
        int l  = l0 + ss;
        int lr = seq_to_lr(k, l);
        float4 r03 = *(const float4*)(drp + (size_t)l * 8);
        float2 r45 = *(const float2*)(drp + (size_t)l * 8 + 4);
        float4 dlt = delta4(r03, r45, wr, bb4);
        float4 u4  = *(const float4*)(up + (size_t)lr * DIN + d0 + cc0);
        float4 B4  = *(const float4*)(bp + (size_t)l * NST + cc0);
        sDU2[cc0 + 0][ss] = make_float2(dlt.x, dlt.x * u4.x);
        sDU2[cc0 + 1][ss] = make_float2(dlt.y, dlt.y * u4.y);
        sDU2[cc0 + 2][ss] = make_float2(dlt.z, dlt.z * u4.z);
        sDU2[cc0 + 3][ss] = make_float2(dlt.w, dlt.w * u4.w);
        sB1t[cc0 + 0][ss] = B4.x;
        sB1t[cc0 + 1][ss] = B4.y;
        sB1t[cc0 + 2][ss] = B4.z;
        sB1t[cc0 + 3][ss] = B4.w;
    }
    __syncthreads();
    float h = 0.0f, P = 1.0f;
#pragma unroll 2
    for (int s4 = 0; s4 < SCH; s4 += 4) {
        float4 duA = *(const float4*)&sDU2[ch][s4];
        float4 duB = *(const float4*)&sDU2[ch][s4 + 2];
        float4 bq  = *(const float4*)&sB1t[n][s4];
        float dA;
        dA = __expf(duA.x * A); h = fmaf(dA, h, duA.y * bq.x); P *= dA;
        dA = __expf(duA.z * A); h = fmaf(dA, h, duA.w * bq.y); P *= dA;
        dA = __expf(duB.x * A); h = fmaf(dA, h, duB.y * bq.z); P *= dA;
        dA = __expf(duB.z * A); h = fmaf(dA, h, duB.w * bq.w); P *= dA;
    }
    sum2[hs_idx(c, (int)kb, d, n)] = make_float2(P, h);
}

// -------- kernel 4b: chunk scan, 4-states/lane + quad-DPP, 64 d per block ----
// 256 threads (4 waves x 16 d), conflict-free layout from R8 (verified: LDS
// bank conflicts 0), occupancy recovered: sY buffer removed (direct scalar y
// stores from ng==0 lanes, 16 consecutive d per wave = 64B segments), lr
// precomputed in a 64-entry LDS table. LDS 42.8 KB -> 3 blocks x 4 waves =
// 12 waves/CU (vs R8's 8).
__global__ __launch_bounds__(256) void k_scanC(
        const float* __restrict__ xi, const float* __restrict__ drbuf,
        const float* __restrict__ Bbuf, const float* __restrict__ Cbuf,
        const float* __restrict__ A_logs, const float* __restrict__ W_dt,
        const float* __restrict__ b_dt,
        const float2* __restrict__ sum2,
        float* __restrict__ ydir) {
    __shared__ float2 sDU2[C_DPB][65];   // [d][s] {delta, delta*u}  33.3 KB
    __shared__ float4 sB4[SCH][5];       // [s][ng] = B[s][ng*4..+3]  5.1 KB
    __shared__ float4 sC4[SCH][5];       // [s][ng]                   5.1 KB
    __shared__ int    sLR[SCH];          // spatial index per step
    int c   = blockIdx.x;
    int blk = blockIdx.y;
    int k   = blk / (BATCH * C_NBLK);
    int rem = blk % (BATCH * C_NBLK);
    int b   = rem / C_NBLK;
    int g   = rem % C_NBLK;
    int d0  = g * C_DPB;
    int t    = threadIdx.x;
    int lane = t & 63, wave = t >> 6;
    int dl   = wave * 16 + (lane >> 2);  // d_local 0..63
    int ng   = lane & 3;
    int n0   = ng * 4;
    int d    = d0 + dl;
    size_t kb = (size_t)(k * BATCH + b);
    const float* drp = drbuf + kb * LL * 8;
    const float* bp  = Bbuf  + kb * LL * NST;
    const float* cp  = Cbuf  + kb * LL * NST;
    const float* up  = xi    + (size_t)b * LL * DIN;
    float*       yp  = ydir  + kb * LL * DIN;     // per-direction slice
    // A for this lane's 4 states
    float4 al = *(const float4*)(A_logs + ((size_t)(k * DIN + d)) * NST + n0);
    float A0 = -__expf(al.x), A1 = -__expf(al.y);
    float A2 = -__expf(al.z), A3 = -__expf(al.w);
    // ---- inline prefix fold: h_in for 4 states (float4-paired loads) ----
    float h0 = 0.f, h1 = 0.f, h2 = 0.f, h3 = 0.f;
    {
        int j = 0;
        for (; j + 4 <= c; j += 4) {
            const float4* p0 = (const float4*)(sum2 + hs_idx(j + 0, (int)kb, d, n0));
            const float4* p1 = (const float4*)(sum2 + hs_idx(j + 1, (int)kb, d, n0));
            const float4* p2 = (const float4*)(sum2 + hs_idx(j + 2, (int)kb, d, n0));
            const float4* p3 = (const float4*)(sum2 + hs_idx(j + 3, (int)kb, d, n0));
            float4 a0 = p0[0], b0 = p0[1];
            float4 a1 = p1[0], b1 = p1[1];
            float4 a2 = p2[0], b2 = p2[1];
            float4 a3 = p3[0], b3 = p3[1];
            h0 = fmaf(a0.x, h0, a0.y); h1 = fmaf(a0.z, h1, a0.w);
            h2 = fmaf(b0.x, h2, b0.y); h3 = fmaf(b0.z, h3, b0.w);
            h0 = fmaf(a1.x, h0, a1.y); h1 = fmaf(a1.z, h1, a1.w);
            h2 = fmaf(b1.x, h2, b1.y); h3 = fmaf(b1.z, h3, b1.w);
            h0 = fmaf(a2.x, h0, a2.y); h1 = fmaf(a2.z, h1, a2.w);
            h2 = fmaf(b2.x, h2, b2.y); h3 = fmaf(b2.z, h3, b2.w);
            h0 = fmaf(a3.x, h0, a3.y); h1 = fmaf(a3.z, h1, a3.w);
            h2 = fmaf(b3.x, h2, b3.y); h3 = fmaf(b3.z, h3, b3.w);
        }
        for (; j < c; j++) {
            const float4* pj = (const float4*)(sum2 + hs_idx(j, (int)kb, d, n0));
            float4 a = pj[0], bq = pj[1];
            h0 = fmaf(a.x, h0, a.y); h1 = fmaf(a.z, h1, a.w);
            h2 = fmaf(bq.x, h2, bq.y); h3 = fmaf(bq.z, h3, bq.w);
        }
    }
    // ---- stage chunk data (256 threads: s = t&63, dg = t>>6) ----
    int l0 = c * SCH;
    {
        int ss = t & 63;
        int dg = t >> 6;             // 0..3 -> d range [dg*16, dg*16+16)
        int l  = l0 + ss;
        int lr = seq_to_lr(k, l);
        if (t < 64) sLR[ss] = lr;
        float4 r03 = *(const float4*)(drp + (size_t)l * 8);
        float2 r45 = *(const float2*)(drp + (size_t)l * 8 + 4);
#pragma unroll
        for (int q = 0; q < 4; q++) {
            int cc0 = dg * 16 + q * 4;
            float4 wr[RNK];
#pragma unroll
            for (int r = 0; r < RNK; r++)
                wr[r] = *(const float4*)(W_dt + ((size_t)k * RNK + r) * DIN + d0 + cc0);
            float4 bb4 = *(const float4*)(b_dt + k * DIN + d0 + cc0);
            float4 dlt = delta4(r03, r45, wr, bb4);
            float4 u4  = *(const float4*)(up + (size_t)lr * DIN + d0 + cc0);
            sDU2[cc0 + 0][ss] = make_float2(dlt.x, dlt.x * u4.x);
            sDU2[cc0 + 1][ss] = make_float2(dlt.y, dlt.y * u4.y);
            sDU2[cc0 + 2][ss] = make_float2(dlt.z, dlt.z * u4.z);
            sDU2[cc0 + 3][ss] = make_float2(dlt.w, dlt.w * u4.w);
        }
        // B / C quads: wave 0 stages B, wave 1 stages C
        if (dg == 0) {
#pragma unroll
            for (int q = 0; q < 4; q++)
                sB4[ss][q] = *(const float4*)(bp + (size_t)l * NST + q * 4);
        } else if (dg == 1) {
#pragma unroll
            for (int q = 0; q < 4; q++)
                sC4[ss][q] = *(const float4*)(cp + (size_t)l * NST + q * 4);
        }
    }
    __syncthreads();
    // ---- main scan: 4 independent h chains per lane, quad reduce ----
    int dglob = d;                       // global d for y stores
#pragma unroll 4
    for (int s = 0; s < SCH; s++) {
        float2 du = sDU2[dl][s];
        float4 B4 = sB4[s][ng];
        float4 C4 = sC4[s][ng];
        h0 = fmaf(__expf(du.x * A0), h0, du.y * B4.x);
        h1 = fmaf(__expf(du.x * A1), h1, du.y * B4.y);
        h2 = fmaf(__expf(du.x * A2), h2, du.y * B4.z);
        h3 = fmaf(__expf(du.x * A3), h3, du.y * B4.w);
        float yq = (h0 * C4.x + h1 * C4.y) + (h2 * C4.z + h3 * C4.w);
        yq += __int_as_float(__builtin_amdgcn_update_dpp(
                0, __float_as_int(yq), 0xB1, 0xf, 0xf, true));  // quad_perm 1,0,3,2
        yq += __int_as_float(__builtin_amdgcn_update_dpp(
                0, __float_as_int(yq), 0x4E, 0xf, 0xf, true));  // quad_perm 2,3,0,1
        if (ng == 0)
            yp[(size_t)sLR[s] * DIN + dglob] = yq;   // 16 consec d per wave
    }
}

// ------- kernel 5: gather 4 directions + D*u + gate + out-projection ---------
constexpr int K5_PIX = 8;
__global__ __launch_bounds__(192) void k_out(
        const float* __restrict__ ydir, const float* __restrict__ xi,
        const float* __restrict__ zbuf, const float* __restrict__ Ds,
        const float* __restrict__ W_out, float* __restrict__ out) {
    __shared__ float g[DIN][12];           // [dd][p] padded
    __shared__ float so[CDIM][9];          // padded stores
    int gp0 = blockIdx.x * K5_PIX;
    int b   = gp0 / LL;
    int l0  = gp0 - b * LL;
    int t   = threadIdx.x;
    for (int i = t; i < K5_PIX * DIN; i += 192) {
        int p = i / DIN, dd = i % DIN;
        size_t off = (size_t)(gp0 + p) * DIN + dd;
        float y = ydir[off] + ydir[SZ_PX + off]
                + ydir[2 * SZ_PX + off] + ydir[3 * SZ_PX + off];
        float dsum = Ds[dd] + Ds[DIN + dd] + Ds[2 * DIN + dd] + Ds[3 * DIN + dd];
        y = fmaf(xi[off], dsum, y);
        g[dd][p] = y * silu(zbuf[off]);
    }
    __syncthreads();
    int f    = t % CDIM;
    int half = t / CDIM;
    float acc[4] = {0.f, 0.f, 0.f, 0.f};
#pragma unroll 4
    for (int dd = 0; dd < DIN; dd++) {
        float wv = W_out[dd * CDIM + f];
        float4 gv = *(const float4*)&g[dd][half * 4];
        acc[0] = fmaf(gv.x, wv, acc[0]);
        acc[1] = fmaf(gv.y, wv, acc[1]);
        acc[2] = fmaf(gv.z, wv, acc[2]);
        acc[3] = fmaf(gv.w, wv, acc[3]);
    }
#pragma unroll
    for (int p = 0; p < 4; p++) so[f][half * 4 + p] = acc[p];
    __syncthreads();
    for (int i = t; i < CDIM * K5_PIX; i += 192) {
        int f2 = i / K5_PIX, p2 = i % K5_PIX;
        out[((size_t)(b * CDIM + f2)) * LL + l0 + p2] = so[f2][p2];
    }
}

// ---------------- launch ----------------------------------------------------
extern "C" void kernel_launch(void* const* d_in, const int* in_sizes, int n_in,
                              void* d_out, int out_size, void* d_ws, size_t ws_size,
                              hipStream_t stream) {
    const float* x       = (const float*)d_in[0];
    const float* W_in    = (const float*)d_in[1];
    const float* W_conv  = (const float*)d_in[2];
    const float* b_conv  = (const float*)d_in[3];
    const float* W_xproj = (const float*)d_in[4];
    const float* W_dt    = (const float*)d_in[5];
    const float* b_dt    = (const float*)d_in[6];
    const float* A_logs  = (const float*)d_in[7];
    const float* Ds      = (const float*)d_in[8];
    const float* W_out   = (const float*)d_in[9];
    float* out = (float*)d_out;
    float* ws  = (float*)d_ws;

    float* xp    = ws + OFF_XP;
    float* z     = ws + OFF_Z;
    float* xi    = ws + OFF_XI;
    float* drbuf = ws + OFF_DR;
    float* Bbuf  = ws + OFF_B;
    float* Cbuf  = ws + OFF_C;
    float* ydir  = ws + OFF_YD;
    float2* sum2 = (float2*)(ws + OFF_HE);
    float* Wt    = ws + OFF_WT;

    k_inproj<<<(BATCH * LL) / K1_PIX, 384, 0, stream>>>(x, W_in, W_xproj, xp, z, Wt);
    k_conv<<<(BATCH * LL) / KC_PIX, 192, 0, stream>>>(xp, W_conv, b_conv, xi);
    dim3 g3((BATCH * LL) / K3_PIX, NK);
    k_xproj<<<g3, 256, 0, stream>>>(xi, Wt, drbuf, Bbuf, Cbuf);
    dim3 gsA(NCH, NK * BATCH * CGRP);
    k_scanA<<<gsA, 256, 0, stream>>>(xi, drbuf, Bbuf, A_logs, W_dt, b_dt, sum2);
    dim3 gsC(NCH, NK * BATCH * C_NBLK);
    k_scanC<<<gsC, 256, 0, stream>>>(xi, drbuf, Bbuf, Cbuf, A_logs, W_dt, b_dt, sum2, ydir);
    k_out<<<(BATCH * LL) / K5_PIX, 192, 0, stream>>>(ydir, xi, z, Ds, W_out, out);
}

// Round 10
// 201.913 us; speedup vs baseline: 1.0204x; 1.0106x over previous
//
#include <hip/hip_runtime.h>
#include <math.h>

// ---------------- problem constants ----------------
constexpr int BATCH  = 2;
constexpr int CDIM   = 96;    // model dim
constexpr int HH     = 56;
constexpr int WW     = 56;
constexpr int LL     = HH * WW;          // 3136
constexpr int DIN    = 192;              // d_inner
constexpr int NK     = 4;                // directions
constexpr int NST    = 16;               // d_state
constexpr int RNK    = 6;                // dt_rank
constexpr int EPROJ  = RNK + 2 * NST;    // 38
constexpr int SCH    = 64;               // steps per scan chunk
constexpr int NCH    = LL / SCH;         // 49 chunks
constexpr int CGRP   = DIN / 16;         // 12 channel-groups of 16

// LDS strides (derived for 16B alignment + <=2-way banks)
constexpr int STDU = SCH + 2;   // float2 rows, stride 66
constexpr int STBC = SCH + 6;   // float2 rows, stride 70
constexpr int STY  = SCH + 4;   // float  rows, stride 68
constexpr int STB1 = SCH + 4;   // float  rows, stride 68

// workspace layout (floats)
constexpr size_t SZ_PX   = (size_t)BATCH * LL * DIN;        // 1,204,224
constexpr size_t OFF_XP  = 0;
constexpr size_t OFF_Z   = OFF_XP + SZ_PX;
constexpr size_t OFF_XI  = OFF_Z  + SZ_PX;
constexpr size_t OFF_DR  = OFF_XI + SZ_PX;                  // dr: [kb][L][8]
constexpr size_t SZ_DR   = (size_t)NK * BATCH * LL * 8;
constexpr size_t OFF_B   = OFF_DR + SZ_DR;                  // B: K*B*L*16
constexpr size_t SZ_BC   = (size_t)NK * BATCH * LL * NST;
constexpr size_t OFF_C   = OFF_B + SZ_BC;
constexpr size_t OFF_YD  = OFF_C + SZ_BC;                   // ydir: [k][b][sp][d]
constexpr size_t SZ_YD   = (size_t)NK * BATCH * LL * DIN;   // 4,816,896
constexpr size_t OFF_HE  = OFF_YD + SZ_YD;                  // (P, h_end) float2 per chunk
constexpr size_t SZ_HS   = (size_t)NK * BATCH * NCH * DIN * NST;
constexpr size_t OFF_WT  = OFF_HE + 2 * SZ_HS;              // Wt: [k][e][d]
constexpr size_t SZ_WT   = (size_t)NK * EPROJ * DIN;        // 29,184

__device__ __forceinline__ float silu(float v) {
    return v / (1.0f + __expf(-v));
}

__device__ __forceinline__ float softplus_f(float x) {
    return (x > 20.0f) ? x : __logf(1.0f + __expf(x));
}

// full 16-lane-row sum via DPP row rotations (VALU only, no LDS pipe).
__device__ __forceinline__ float row_reduce16(float p) {
    p += __int_as_float(__builtin_amdgcn_update_dpp(0, __float_as_int(p), 0x128, 0xf, 0xf, true));
    p += __int_as_float(__builtin_amdgcn_update_dpp(0, __float_as_int(p), 0x124, 0xf, 0xf, true));
    p += __int_as_float(__builtin_amdgcn_update_dpp(0, __float_as_int(p), 0x122, 0xf, 0xf, true));
    p += __int_as_float(__builtin_amdgcn_update_dpp(0, __float_as_int(p), 0x121, 0xf, 0xf, true));
    return p;
}

// direction k, sequence position l -> row-major spatial index
__device__ __forceinline__ int seq_to_lr(int k, int l) {
    int q = l / WW;
    int r = l - q * WW;
    if (k == 0) return l;
    if (k == 1) return q * WW + (WW - 1 - r);
    if (k == 2) return r * WW + q;
    return (WW - 1 - r) * WW + q;
}

// direction k, row-major spatial index s -> sequence position (inverse map)
__device__ __forceinline__ int spatial_to_seq(int k, int s) {
    int h = s / WW;
    int w = s - h * WW;
    if (k == 0) return s;
    if (k == 1) return h * WW + (WW - 1 - w);
    if (k == 2) return w * WW + h;
    return w * WW + (WW - 1 - h);
}

// chunk-summary index: [c][kb][d][n]
__device__ __forceinline__ size_t hs_idx(int c, int kb, int d, int n) {
    return ((size_t)(c * (NK * BATCH) + kb) * DIN + d) * NST + n;
}

// rank-6 delta: vectorized over 4 consecutive d (components of float4)
__device__ __forceinline__ float4 delta4(
        float4 r03, float2 r45, const float4* wr, float4 bb4) {
    float4 raw = bb4;
    raw.x = fmaf(r03.x, wr[0].x, raw.x); raw.y = fmaf(r03.x, wr[0].y, raw.y);
    raw.z = fmaf(r03.x, wr[0].z, raw.z); raw.w = fmaf(r03.x, wr[0].w, raw.w);
    raw.x = fmaf(r03.y, wr[1].x, raw.x); raw.y = fmaf(r03.y, wr[1].y, raw.y);
    raw.z = fmaf(r03.y, wr[1].z, raw.z); raw.w = fmaf(r03.y, wr[1].w, raw.w);
    raw.x = fmaf(r03.z, wr[2].x, raw.x); raw.y = fmaf(r03.z, wr[2].y, raw.y);
    raw.z = fmaf(r03.z, wr[2].z, raw.z); raw.w = fmaf(r03.z, wr[2].w, raw.w);
    raw.x = fmaf(r03.w, wr[3].x, raw.x); raw.y = fmaf(r03.w, wr[3].y, raw.y);
    raw.z = fmaf(r03.w, wr[3].z, raw.z); raw.w = fmaf(r03.w, wr[3].w, raw.w);
    raw.x = fmaf(r45.x, wr[4].x, raw.x); raw.y = fmaf(r45.x, wr[4].y, raw.y);
    raw.z = fmaf(r45.x, wr[4].z, raw.z); raw.w = fmaf(r45.x, wr[4].w, raw.w);
    raw.x = fmaf(r45.y, wr[5].x, raw.x); raw.y = fmaf(r45.y, wr[5].y, raw.y);
    raw.z = fmaf(r45.y, wr[5].z, raw.z); raw.w = fmaf(r45.y, wr[5].w, raw.w);
    raw.x = softplus_f(raw.x); raw.y = softplus_f(raw.y);
    raw.z = softplus_f(raw.z); raw.w = softplus_f(raw.w);
    return raw;
}

// ---------------- kernel 1: in-projection (x^T @ W_in -> xp, z) --------------
// Side job: first threads also transpose W_xproj -> Wt[k][e][d].
constexpr int K1_PIX = 8;
__global__ __launch_bounds__(384) void k_inproj(
        const float* __restrict__ x, const float* __restrict__ W_in,
        const float* __restrict__ W_xproj,
        float* __restrict__ xp, float* __restrict__ z, float* __restrict__ Wt) {
    __shared__ float sxT[CDIM][K1_PIX];   // [c][p], 3 KB
    int gp0 = blockIdx.x * K1_PIX;      // global pixel = b*LL + l
    int t   = threadIdx.x;
    int b   = gp0 / LL;
    int l0  = gp0 - b * LL;
    int gid = blockIdx.x * 384 + t;
    if (gid < NK * DIN * EPROJ) {
        int k = gid / (DIN * EPROJ);
        int r = gid % (DIN * EPROJ);
        int d = r / EPROJ;
        int e = r % EPROJ;
        Wt[((size_t)k * EPROJ + e) * DIN + d] = W_xproj[gid];
    }
    for (int i = t; i < CDIM * K1_PIX; i += 384) {
        int c = i >> 3, p = i & 7;
        sxT[c][p] = x[((size_t)(b * CDIM + c)) * LL + l0 + p];
    }
    __syncthreads();
    int e = t;                          // 0..383 output feature
    float acc[K1_PIX];
#pragma unroll
    for (int p = 0; p < K1_PIX; p++) acc[p] = 0.0f;
    const float4* sx4 = (const float4*)sxT;
#pragma unroll 4
    for (int c = 0; c < CDIM; c++) {
        float w  = W_in[c * (2 * DIN) + e];
        float4 va = sx4[2 * c];
        float4 vb = sx4[2 * c + 1];
        acc[0] = fmaf(va.x, w, acc[0]); acc[1] = fmaf(va.y, w, acc[1]);
        acc[2] = fmaf(va.z, w, acc[2]); acc[3] = fmaf(va.w, w, acc[3]);
        acc[4] = fmaf(vb.x, w, acc[4]); acc[5] = fmaf(vb.y, w, acc[5]);
        acc[6] = fmaf(vb.z, w, acc[6]); acc[7] = fmaf(vb.w, w, acc[7]);
    }
    if (e < DIN) {
#pragma unroll
        for (int p = 0; p < K1_PIX; p++)
            xp[((size_t)(gp0 + p)) * DIN + e] = acc[p];
    } else {
        int e2 = e - DIN;
#pragma unroll
        for (int p = 0; p < K1_PIX; p++)
            z[((size_t)(gp0 + p)) * DIN + e2] = acc[p];
    }
}

// ---------------- kernel 2: depthwise conv 3x3 + bias + SiLU ----------------
// Vectorized float4 over channels (G13): 4 pixels/block, 48 ch-groups,
// weights staged transposed in LDS.
constexpr int KC_PIX = 4;
__global__ __launch_bounds__(192) void k_conv(
        const float* __restrict__ xp, const float* __restrict__ Wc,
        const float* __restrict__ bc, float* __restrict__ xi) {
    __shared__ float sW[9][DIN];          // 6.9 KB, transposed weights
    int t = threadIdx.x;
    for (int i = t; i < DIN * 9; i += 192) {
        int d = i / 9, tap = i % 9;
        sW[tap][d] = Wc[i];
    }
    __syncthreads();
    int p   = t / 48;            // pixel within block 0..3
    int cg4 = (t % 48) * 4;      // channel quad
    int gp  = blockIdx.x * KC_PIX + p;
    int b   = gp / LL;
    int l   = gp - b * LL;
    int h   = l / WW;
    int w   = l - h * WW;
    float4 acc = *(const float4*)&bc[cg4];
#pragma unroll
    for (int dy = -1; dy <= 1; dy++) {
        int hh = h + dy;
        if (hh < 0 || hh >= HH) continue;
#pragma unroll
        for (int dx = -1; dx <= 1; dx++) {
            int ww = w + dx;
            if (ww < 0 || ww >= WW) continue;
            float4 xv = *(const float4*)&xp[((size_t)b * LL + hh * WW + ww) * DIN + cg4];
            float4 wv = *(const float4*)&sW[(dy + 1) * 3 + (dx + 1)][cg4];
            acc.x = fmaf(xv.x, wv.x, acc.x);
            acc.y = fmaf(xv.y, wv.y, acc.y);
            acc.z = fmaf(xv.z, wv.z, acc.z);
            acc.w = fmaf(xv.w, wv.w, acc.w);
        }
    }
    float4 o;
    o.x = silu(acc.x); o.y = silu(acc.y); o.z = silu(acc.z); o.w = silu(acc.w);
    *(float4*)&xi[(size_t)gp * DIN + cg4] = o;
}

// ------- kernel 3: x-proj -> dr (rank-6), B, C ------------------------------
// Weights read straight from L1/L2 (29 KB per direction, shared by all 196
// blocks of that direction; 16-lane broadcast rows).
constexpr int K3_PIX = 32;
__global__ __launch_bounds__(256) void k_xproj(
        const float* __restrict__ xi, const float* __restrict__ Wt,
        float* __restrict__ drbuf, float* __restrict__ Bbuf,
        float* __restrict__ Cbuf) {
    __shared__ float4 v4[K3_PIX][49];    // 25.1 KB
    int k   = blockIdx.y;
    int gp0 = blockIdx.x * K3_PIX;
    int b   = gp0 / LL;
    int l0  = gp0 - b * LL;
    int t   = threadIdx.x;
    const float4* xin4 = (const float4*)(xi + (size_t)gp0 * DIN);
    for (int i = t; i < K3_PIX * 48; i += 256)
        v4[i / 48][i % 48] = xin4[i];
    const float4* wt4 = (const float4*)(Wt + (size_t)k * EPROJ * DIN);
    __syncthreads();
    int p0 = t & 15;            // pixel within 16-set
    int eg = t >> 4;            // e-group 0..15
    bool has3 = (eg < EPROJ - 32);      // eg < 6
    float acc[2][3] = {{0.f, 0.f, 0.f}, {0.f, 0.f, 0.f}};
#pragma unroll 4
    for (int j = 0; j < 48; j++) {
        float4 w0 = wt4[eg * 48 + j];
        float4 w1 = wt4[(eg + 16) * 48 + j];
        float4 w2 = has3 ? wt4[(eg + 32) * 48 + j] : make_float4(0.f, 0.f, 0.f, 0.f);
#pragma unroll
        for (int q = 0; q < 2; q++) {
            float4 vv = v4[p0 + 16 * q][j];
            acc[q][0] = fmaf(vv.x, w0.x, acc[q][0]); acc[q][0] = fmaf(vv.y, w0.y, acc[q][0]);
            acc[q][0] = fmaf(vv.z, w0.z, acc[q][0]); acc[q][0] = fmaf(vv.w, w0.w, acc[q][0]);
            acc[q][1] = fmaf(vv.x, w1.x, acc[q][1]); acc[q][1] = fmaf(vv.y, w1.y, acc[q][1]);
            acc[q][1] = fmaf(vv.z, w1.z, acc[q][1]); acc[q][1] = fmaf(vv.w, w1.w, acc[q][1]);
            acc[q][2] = fmaf(vv.x, w2.x, acc[q][2]); acc[q][2] = fmaf(vv.y, w2.y, acc[q][2]);
            acc[q][2] = fmaf(vv.z, w2.z, acc[q][2]); acc[q][2] = fmaf(vv.w, w2.w, acc[q][2]);
        }
    }
#pragma unroll
    for (int q = 0; q < 2; q++) {
        int p  = p0 + 16 * q;
        int ls = spatial_to_seq(k, l0 + p);
        size_t kb  = (size_t)(k * BATCH + b);
        size_t b8  = (kb * LL + ls) * 8;
        size_t b16 = (kb * LL + ls) * NST;
        if (eg < RNK) drbuf[b8 + eg] = acc[q][0];
        else          Bbuf[b16 + eg - RNK] = acc[q][0];
        int e1 = eg + 16;
        if (e1 < RNK + NST) Bbuf[b16 + e1 - RNK] = acc[q][1];
        else                Cbuf[b16 + e1 - RNK - NST] = acc[q][1];
        if (has3) Cbuf[b16 + eg + 32 - RNK - NST] = acc[q][2];
    }
}

// -------- kernel 4a: chunk-local scan -> per-chunk summary (P, h_end) --------
// R5-proven serial form; summary stored interleaved float2 {P, h}.
__global__ __launch_bounds__(256) void k_scanA(
        const float* __restrict__ xi, const float* __restrict__ drbuf,
        const float* __restrict__ Bbuf, const float* __restrict__ A_logs,
        const float* __restrict__ W_dt, const float* __restrict__ b_dt,
        float2* __restrict__ sum2) {
    __shared__ float2 sDU2[16][STDU];   // [ch][s] {delta, delta*u}
    __shared__ float  sB1t[16][STB1];   // [n][s]
    int c   = blockIdx.x;
    int blk = blockIdx.y;
    int k   = blk / (BATCH * CGRP);
    int rem = blk % (BATCH * CGRP);
    int b   = rem / CGRP;
    int cg  = rem % CGRP;
    int d0  = cg * 16;
    int t    = threadIdx.x;
    int lane = t & 63, wave = t >> 6;
    int grp  = lane >> 4, n = lane & 15;
    int ch   = wave * 4 + grp;
    int d    = d0 + ch;
    float A = -__expf(A_logs[((size_t)(k * DIN + d)) * NST + n]);
    size_t kb = (size_t)(k * BATCH + b);
    const float* drp = drbuf + kb * LL * 8;
    const float* bp  = Bbuf  + kb * LL * NST;
    const float* up  = xi    + (size_t)b * LL * DIN;
    // staging identity
    int ss  = t >> 2;            // 0..63
    int cc0 = (t & 3) * 4;       // 0,4,8,12
    float4 wr[RNK];
#pragma unroll
    for (int r = 0; r < RNK; r++)
        wr[r] = *(const float4*)(W_dt + ((size_t)k * RNK + r) * DIN + d0 + cc0);
    float4 bb4 = *(const float4*)(b_dt + k * DIN + d0 + cc0);
    int l0 = c * SCH;
    {
        int l  = l0 + ss;
        int lr = seq_to_lr(k, l);
        float4 r03 = *(const float4*)(drp + (size_t)l * 8);
        float2 r45 = *(const float2*)(drp + (size_t)l * 8 + 4);
        float4 dlt = delta4(r03, r45, wr, bb4);
        float4 u4  = *(const float4*)(up + (size_t)lr * DIN + d0 + cc0);
        float4 B4  = *(const float4*)(bp + (size_t)l * NST + cc0);
        sDU2[cc0 + 0][ss] = make_float2(dlt.x, dlt.x * u4.x);
        sDU2[cc0 + 1][ss] = make_float2(dlt.y, dlt.y * u4.y);
        sDU2[cc0 + 2][ss] = make_float2(dlt.z, dlt.z * u4.z);
        sDU2[cc0 + 3][ss] = make_float2(dlt.w, dlt.w * u4.w);
        sB1t[cc0 + 0][ss] = B4.x;
        sB1t[cc0 + 1][ss] = B4.y;
        sB1t[cc0 + 2][ss] = B4.z;
        sB1t[cc0 + 3][ss] = B4.w;
    }
    __syncthreads();
    float h = 0.0f, P = 1.0f;
#pragma unroll 2
    for (int s4 = 0; s4 < SCH; s4 += 4) {
        float4 duA = *(const float4*)&sDU2[ch][s4];
        float4 duB = *(const float4*)&sDU2[ch][s4 + 2];
        float4 bq  = *(const float4*)&sB1t[n][s4];
        float dA;
        dA = __expf(duA.x * A); h = fmaf(dA, h, duA.y * bq.x); P *= dA;
        dA = __expf(duA.z * A); h = fmaf(dA, h, duA.w * bq.y); P *= dA;
        dA = __expf(duB.x * A); h = fmaf(dA, h, duB.y * bq.z); P *= dA;
        dA = __expf(duB.z * A); h = fmaf(dA, h, duB.w * bq.w); P *= dA;
    }
    sum2[hs_idx(c, (int)kb, d, n)] = make_float2(P, h);
}

// -------- kernel 4b: chunk-local scan with inline prefix fold; emit y --------
// R5-proven version: fold unrolled x8, DPP-16 y reduction, float4 writeback.
__global__ __launch_bounds__(256) void k_scanC(
        const float* __restrict__ xi, const float* __restrict__ drbuf,
        const float* __restrict__ Bbuf, const float* __restrict__ Cbuf,
        const float* __restrict__ A_logs, const float* __restrict__ W_dt,
        const float* __restrict__ b_dt,
        const float2* __restrict__ sum2,
        float* __restrict__ ydir) {
    __shared__ float2 sDU2[16][STDU];   // [ch][s] {delta, delta*u}
    __shared__ float2 sBC2[16][STBC];   // [n][s]  {B, C}
    __shared__ float  sY[16][STY];      // [ch][s]
    int c   = blockIdx.x;
    int blk = blockIdx.y;
    int k   = blk / (BATCH * CGRP);
    int rem = blk % (BATCH * CGRP);
    int b   = rem / CGRP;
    int cg  = rem % CGRP;
    int d0  = cg * 16;
    int t    = threadIdx.x;
    int lane = t & 63, wave = t >> 6;
    int grp  = lane >> 4, n = lane & 15;
    int ch   = wave * 4 + grp;
    int d    = d0 + ch;
    float A = -__expf(A_logs[((size_t)(k * DIN + d)) * NST + n]);
    size_t kb = (size_t)(k * BATCH + b);
    const float* drp = drbuf + kb * LL * 8;
    const float* bp  = Bbuf  + kb * LL * NST;
    const float* cp  = Cbuf  + kb * LL * NST;
    const float* up  = xi    + (size_t)b * LL * DIN;
    float*       yp  = ydir  + kb * LL * DIN;     // per-direction slice
    // ---- inline prefix fold: h_in for this (d, n) over chunks 0..c-1 ----
    float hin = 0.0f;
    {
        int j = 0;
        for (; j + 8 <= c; j += 8) {
            float2 a0 = sum2[hs_idx(j + 0, (int)kb, d, n)];
            float2 a1 = sum2[hs_idx(j + 1, (int)kb, d, n)];
            float2 a2 = sum2[hs_idx(j + 2, (int)kb, d, n)];
            float2 a3 = sum2[hs_idx(j + 3, (int)kb, d, n)];
            float2 a4 = sum2[hs_idx(j + 4, (int)kb, d, n)];
            float2 a5 = sum2[hs_idx(j + 5, (int)kb, d, n)];
            float2 a6 = sum2[hs_idx(j + 6, (int)kb, d, n)];
            float2 a7 = sum2[hs_idx(j + 7, (int)kb, d, n)];
            hin = fmaf(a0.x, hin, a0.y);
            hin = fmaf(a1.x, hin, a1.y);
            hin = fmaf(a2.x, hin, a2.y);
            hin = fmaf(a3.x, hin, a3.y);
            hin = fmaf(a4.x, hin, a4.y);
            hin = fmaf(a5.x, hin, a5.y);
            hin = fmaf(a6.x, hin, a6.y);
            hin = fmaf(a7.x, hin, a7.y);
        }
        for (; j < c; j++) {
            float2 a = sum2[hs_idx(j, (int)kb, d, n)];
            hin = fmaf(a.x, hin, a.y);
        }
    }
    // ---- stage chunk data ----
    int ss  = t >> 2;
    int cc0 = (t & 3) * 4;
    float4 wr[RNK];
#pragma unroll
    for (int r = 0; r < RNK; r++)
        wr[r] = *(const float4*)(W_dt + ((size_t)k * RNK + r) * DIN + d0 + cc0);
    float4 bb4 = *(const float4*)(b_dt + k * DIN + d0 + cc0);
    int l0 = c * SCH;
    {
        int l  = l0 + ss;
        int lr = seq_to_lr(k, l);
        float4 r03 = *(const float4*)(drp + (size_t)l * 8);
        float2 r45 = *(const float2*)(drp + (size_t)l * 8 + 4);
        float4 dlt = delta4(r03, r45, wr, bb4);
        float4 u4  = *(const float4*)(up + (size_t)lr * DIN + d0 + cc0);
        float4 B4  = *(const float4*)(bp + (size_t)l * NST + cc0);
        float4 C4  = *(const float4*)(cp + (size_t)l * NST + cc0);
        sDU2[cc0 + 0][ss] = make_float2(dlt.x, dlt.x * u4.x);
        sDU2[cc0 + 1][ss] = make_float2(dlt.y, dlt.y * u4.y);
        sDU2[cc0 + 2][ss] = make_float2(dlt.z, dlt.z * u4.z);
        sDU2[cc0 + 3][ss] = make_float2(dlt.w, dlt.w * u4.w);
        sBC2[cc0 + 0][ss] = make_float2(B4.x, C4.x);
        sBC2[cc0 + 1][ss] = make_float2(B4.y, C4.y);
        sBC2[cc0 + 2][ss] = make_float2(B4.z, C4.z);
        sBC2[cc0 + 3][ss] = make_float2(B4.w, C4.w);
    }
    __syncthreads();
    float h = hin;
#pragma unroll 2
    for (int s4 = 0; s4 < SCH; s4 += 4) {
        float4 duA = *(const float4*)&sDU2[ch][s4];
        float4 duB = *(const float4*)&sDU2[ch][s4 + 2];
        float4 bcA = *(const float4*)&sBC2[n][s4];
        float4 bcB = *(const float4*)&sBC2[n][s4 + 2];
        float dA, y0, y1, y2, y3;
        dA = __expf(duA.x * A); h = fmaf(dA, h, duA.y * bcA.x); y0 = row_reduce16(h * bcA.y);
        dA = __expf(duA.z * A); h = fmaf(dA, h, duA.w * bcA.z); y1 = row_reduce16(h * bcA.w);
        dA = __expf(duB.x * A); h = fmaf(dA, h, duB.y * bcB.x); y2 = row_reduce16(h * bcB.y);
        dA = __expf(duB.z * A); h = fmaf(dA, h, duB.w * bcB.z); y3 = row_reduce16(h * bcB.w);
        if (n == 0) *(float4*)&sY[ch][s4] = make_float4(y0, y1, y2, y3);
    }
    __syncthreads();
    // vectorized writeback: one float4 store per thread (s = t>>2, quad = t&3)
    {
        int s  = t >> 2;
        int c4 = (t & 3) * 4;
        int lr = seq_to_lr(k, l0 + s);
        float4 v = make_float4(sY[c4 + 0][s], sY[c4 + 1][s],
                               sY[c4 + 2][s], sY[c4 + 3][s]);
        *(float4*)&yp[(size_t)lr * DIN + d0 + c4] = v;
    }
}

// ------- kernel 5: gather 4 directions + D*u + gate + out-projection ---------
// Gather vectorized (G13): dsum hoisted to LDS once; float4 loads for
// ydir/xi/z. p-fastest index order keeps each 128B line fully covered by a
// wave; LDS g writes stay at the original 4-way conflict level.
constexpr int K5_PIX = 8;
__global__ __launch_bounds__(192) void k_out(
        const float* __restrict__ ydir, const float* __restrict__ xi,
        const float* __restrict__ zbuf, const float* __restrict__ Ds,
        const float* __restrict__ W_out, float* __restrict__ out) {
    __shared__ float g[DIN][12];           // [dd][p] padded
    __shared__ float so[CDIM][9];          // padded stores
    __shared__ float sDs[DIN];             // summed D per channel
    int gp0 = blockIdx.x * K5_PIX;
    int b   = gp0 / LL;
    int l0  = gp0 - b * LL;
    int t   = threadIdx.x;
    if (t < DIN / 4) {
        int dd = t * 4;
        float4 e0 = *(const float4*)&Ds[dd];
        float4 e1 = *(const float4*)&Ds[DIN + dd];
        float4 e2 = *(const float4*)&Ds[2 * DIN + dd];
        float4 e3 = *(const float4*)&Ds[3 * DIN + dd];
        float4 s;
        s.x = e0.x + e1.x + e2.x + e3.x;
        s.y = e0.y + e1.y + e2.y + e3.y;
        s.z = e0.z + e1.z + e2.z + e3.z;
        s.w = e0.w + e1.w + e2.w + e3.w;
        *(float4*)&sDs[dd] = s;
    }
    __syncthreads();
    for (int i = t; i < K5_PIX * (DIN / 4); i += 192) {
        int p  = i & (K5_PIX - 1);
        int q4 = (i >> 3) * 4;
        size_t off = (size_t)(gp0 + p) * DIN + q4;
        float4 y0 = *(const float4*)&ydir[off];
        float4 y1 = *(const float4*)&ydir[SZ_PX + off];
        float4 y2 = *(const float4*)&ydir[2 * SZ_PX + off];
        float4 y3 = *(const float4*)&ydir[3 * SZ_PX + off];
        float4 xv = *(const float4*)&xi[off];
        float4 zv = *(const float4*)&zbuf[off];
        float4 ds = *(const float4*)&sDs[q4];
        float yx = ((y0.x + y1.x) + y2.x) + y3.x;
        float yy = ((y0.y + y1.y) + y2.y) + y3.y;
        float yz = ((y0.z + y1.z) + y2.z) + y3.z;
        float yw = ((y0.w + y1.w) + y2.w) + y3.w;
        yx = fmaf(xv.x, ds.x, yx);
        yy = fmaf(xv.y, ds.y, yy);
        yz = fmaf(xv.z, ds.z, yz);
        yw = fmaf(xv.w, ds.w, yw);
        g[q4 + 0][p] = yx * silu(zv.x);
        g[q4 + 1][p] = yy * silu(zv.y);
        g[q4 + 2][p] = yz * silu(zv.z);
        g[q4 + 3][p] = yw * silu(zv.w);
    }
    __syncthreads();
    int f    = t % CDIM;
    int half = t / CDIM;
    float acc[4] = {0.f, 0.f, 0.f, 0.f};
#pragma unroll 4
    for (int dd = 0; dd < DIN; dd++) {
        float wv = W_out[dd * CDIM + f];
        float4 gv = *(const float4*)&g[dd][half * 4];
        acc[0] = fmaf(gv.x, wv, acc[0]);
        acc[1] = fmaf(gv.y, wv, acc[1]);
        acc[2] = fmaf(gv.z, wv, acc[2]);
        acc[3] = fmaf(gv.w, wv, acc[3]);
    }
#pragma unroll
    for (int p = 0; p < 4; p++) so[f][half * 4 + p] = acc[p];
    __syncthreads();
    for (int i = t; i < CDIM * K5_PIX; i += 192) {
        int f2 = i / K5_PIX, p2 = i % K5_PIX;
        out[((size_t)(b * CDIM + f2)) * LL + l0 + p2] = so[f2][p2];
    }
}

// ---------------- launch ----------------------------------------------------
extern "C" void kernel_launch(void* const* d_in, const int* in_sizes, int n_in,
                              void* d_out, int out_size, void* d_ws, size_t ws_size,
                              hipStream_t stream) {
    const float* x       = (const float*)d_in[0];
    const float* W_in    = (const float*)d_in[1];
    const float* W_conv  = (const float*)d_in[2];
    const float* b_conv  = (const float*)d_in[3];
    const float* W_xproj = (const float*)d_in[4];
    const float* W_dt    = (const float*)d_in[5];
    const float* b_dt    = (const float*)d_in[6];
    const float* A_logs  = (const float*)d_in[7];
    const float* Ds      = (const float*)d_in[8];
    const float* W_out   = (const float*)d_in[9];
    float* out = (float*)d_out;
    float* ws  = (float*)d_ws;

    float* xp    = ws + OFF_XP;
    float* z     = ws + OFF_Z;
    float* xi    = ws + OFF_XI;
    float* drbuf = ws + OFF_DR;
    float* Bbuf  = ws + OFF_B;
    float* Cbuf  = ws + OFF_C;
    float* ydir  = ws + OFF_YD;
    float2* sum2 = (float2*)(ws + OFF_HE);
    float* Wt    = ws + OFF_WT;

    k_inproj<<<(BATCH * LL) / K1_PIX, 384, 0, stream>>>(x, W_in, W_xproj, xp, z, Wt);
    k_conv<<<(BATCH * LL) / KC_PIX, 192, 0, stream>>>(xp, W_conv, b_conv, xi);
    dim3 g3((BATCH * LL) / K3_PIX, NK);
    k_xproj<<<g3, 256, 0, stream>>>(xi, Wt, drbuf, Bbuf, Cbuf);
    dim3 gs(NCH, NK * BATCH * CGRP);
    k_scanA<<<gs, 256, 0, stream>>>(xi, drbuf, Bbuf, A_logs, W_dt, b_dt, sum2);
    k_scanC<<<gs, 256, 0, stream>>>(xi, drbuf, Bbuf, Cbuf, A_logs, W_dt, b_dt, sum2, ydir);
    k_out<<<(BATCH * LL) / K5_PIX, 192, 0, stream>>>(ydir, xi, z, Ds, W_out, out);
}

// Round 11
// 200.335 us; speedup vs baseline: 1.0284x; 1.0079x over previous
//
#include <hip/hip_runtime.h>
#include <math.h>

// ---------------- problem constants ----------------
constexpr int BATCH  = 2;
constexpr int CDIM   = 96;    // model dim
constexpr int HH     = 56;
constexpr int WW     = 56;
constexpr int LL     = HH * WW;          // 3136
constexpr int DIN    = 192;              // d_inner
constexpr int NK     = 4;                // directions
constexpr int NST    = 16;               // d_state
constexpr int RNK    = 6;                // dt_rank
constexpr int EPROJ  = RNK + 2 * NST;    // 38
constexpr int SCH    = 64;               // steps per scan chunk
constexpr int NCH    = LL / SCH;         // 49 chunks
constexpr int CGRP   = DIN / 16;         // 12 channel-groups of 16

// LDS strides (derived for 16B alignment + <=2-way banks)
constexpr int STDU = SCH + 2;   // float2 rows, stride 66
constexpr int STBC = SCH + 6;   // float2 rows, stride 70
constexpr int STY  = SCH + 4;   // float  rows, stride 68
constexpr int STB1 = SCH + 4;   // float  rows, stride 68

// workspace layout (floats)
constexpr size_t SZ_PX   = (size_t)BATCH * LL * DIN;        // 1,204,224
constexpr size_t OFF_XP  = 0;
constexpr size_t OFF_Z   = OFF_XP + SZ_PX;
constexpr size_t OFF_XI  = OFF_Z  + SZ_PX;
constexpr size_t OFF_DR  = OFF_XI + SZ_PX;                  // dr: [kb][L][8]
constexpr size_t SZ_DR   = (size_t)NK * BATCH * LL * 8;
constexpr size_t OFF_B   = OFF_DR + SZ_DR;                  // B: K*B*L*16
constexpr size_t SZ_BC   = (size_t)NK * BATCH * LL * NST;
constexpr size_t OFF_C   = OFF_B + SZ_BC;
constexpr size_t OFF_YD  = OFF_C + SZ_BC;                   // ydir: [k][b][sp][d]
constexpr size_t SZ_YD   = (size_t)NK * BATCH * LL * DIN;   // 4,816,896
constexpr size_t OFF_HE  = OFF_YD + SZ_YD;                  // (P, h_end) float2 per chunk
constexpr size_t SZ_HS   = (size_t)NK * BATCH * NCH * DIN * NST;
constexpr size_t OFF_WT  = OFF_HE + 2 * SZ_HS;              // Wt: [k][e][d]
constexpr size_t SZ_WT   = (size_t)NK * EPROJ * DIN;        // 29,184

__device__ __forceinline__ float silu(float v) {
    return v / (1.0f + __expf(-v));
}

__device__ __forceinline__ float softplus_f(float x) {
    return (x > 20.0f) ? x : __logf(1.0f + __expf(x));
}

// full 16-lane-row sum via DPP row rotations (VALU only, no LDS pipe).
__device__ __forceinline__ float row_reduce16(float p) {
    p += __int_as_float(__builtin_amdgcn_update_dpp(0, __float_as_int(p), 0x128, 0xf, 0xf, true));
    p += __int_as_float(__builtin_amdgcn_update_dpp(0, __float_as_int(p), 0x124, 0xf, 0xf, true));
    p += __int_as_float(__builtin_amdgcn_update_dpp(0, __float_as_int(p), 0x122, 0xf, 0xf, true));
    p += __int_as_float(__builtin_amdgcn_update_dpp(0, __float_as_int(p), 0x121, 0xf, 0xf, true));
    return p;
}

// direction k, sequence position l -> row-major spatial index
__device__ __forceinline__ int seq_to_lr(int k, int l) {
    int q = l / WW;
    int r = l - q * WW;
    if (k == 0) return l;
    if (k == 1) return q * WW + (WW - 1 - r);
    if (k == 2) return r * WW + q;
    return (WW - 1 - r) * WW + q;
}

// direction k, row-major spatial index s -> sequence position (inverse map)
__device__ __forceinline__ int spatial_to_seq(int k, int s) {
    int h = s / WW;
    int w = s - h * WW;
    if (k == 0) return s;
    if (k == 1) return h * WW + (WW - 1 - w);
    if (k == 2) return w * WW + h;
    return w * WW + (WW - 1 - h);
}

// chunk-summary index: [c][kb][d][n]
__device__ __forceinline__ size_t hs_idx(int c, int kb, int d, int n) {
    return ((size_t)(c * (NK * BATCH) + kb) * DIN + d) * NST + n;
}

// rank-6 delta: vectorized over 4 consecutive d (components of float4)
__device__ __forceinline__ float4 delta4(
        float4 r03, float2 r45, const float4* wr, float4 bb4) {
    float4 raw = bb4;
    raw.x = fmaf(r03.x, wr[0].x, raw.x); raw.y = fmaf(r03.x, wr[0].y, raw.y);
    raw.z = fmaf(r03.x, wr[0].z, raw.z); raw.w = fmaf(r03.x, wr[0].w, raw.w);
    raw.x = fmaf(r03.y, wr[1].x, raw.x); raw.y = fmaf(r03.y, wr[1].y, raw.y);
    raw.z = fmaf(r03.y, wr[1].z, raw.z); raw.w = fmaf(r03.y, wr[1].w, raw.w);
    raw.x = fmaf(r03.z, wr[2].x, raw.x); raw.y = fmaf(r03.z, wr[2].y, raw.y);
    raw.z = fmaf(r03.z, wr[2].z, raw.z); raw.w = fmaf(r03.z, wr[2].w, raw.w);
    raw.x = fmaf(r03.w, wr[3].x, raw.x); raw.y = fmaf(r03.w, wr[3].y, raw.y);
    raw.z = fmaf(r03.w, wr[3].z, raw.z); raw.w = fmaf(r03.w, wr[3].w, raw.w);
    raw.x = fmaf(r45.x, wr[4].x, raw.x); raw.y = fmaf(r45.x, wr[4].y, raw.y);
    raw.z = fmaf(r45.x, wr[4].z, raw.z); raw.w = fmaf(r45.x, wr[4].w, raw.w);
    raw.x = fmaf(r45.y, wr[5].x, raw.x); raw.y = fmaf(r45.y, wr[5].y, raw.y);
    raw.z = fmaf(r45.y, wr[5].z, raw.z); raw.w = fmaf(r45.y, wr[5].w, raw.w);
    raw.x = softplus_f(raw.x); raw.y = softplus_f(raw.y);
    raw.z = softplus_f(raw.z); raw.w = softplus_f(raw.w);
    return raw;
}

// ---------------- kernel 1: in-projection (x^T @ W_in -> xp, z) --------------
// Side job: first threads also transpose W_xproj -> Wt[k][e][d].
constexpr int K1_PIX = 8;
__global__ __launch_bounds__(384) void k_inproj(
        const float* __restrict__ x, const float* __restrict__ W_in,
        const float* __restrict__ W_xproj,
        float* __restrict__ xp, float* __restrict__ z, float* __restrict__ Wt) {
    __shared__ float sxT[CDIM][K1_PIX];   // [c][p], 3 KB
    int gp0 = blockIdx.x * K1_PIX;      // global pixel = b*LL + l
    int t   = threadIdx.x;
    int b   = gp0 / LL;
    int l0  = gp0 - b * LL;
    int gid = blockIdx.x * 384 + t;
    if (gid < NK * DIN * EPROJ) {
        int k = gid / (DIN * EPROJ);
        int r = gid % (DIN * EPROJ);
        int d = r / EPROJ;
        int e = r % EPROJ;
        Wt[((size_t)k * EPROJ + e) * DIN + d] = W_xproj[gid];
    }
    for (int i = t; i < CDIM * K1_PIX; i += 384) {
        int c = i >> 3, p = i & 7;
        sxT[c][p] = x[((size_t)(b * CDIM + c)) * LL + l0 + p];
    }
    __syncthreads();
    int e = t;                          // 0..383 output feature
    float acc[K1_PIX];
#pragma unroll
    for (int p = 0; p < K1_PIX; p++) acc[p] = 0.0f;
    const float4* sx4 = (const float4*)sxT;
#pragma unroll 4
    for (int c = 0; c < CDIM; c++) {
        float w  = W_in[c * (2 * DIN) + e];
        float4 va = sx4[2 * c];
        float4 vb = sx4[2 * c + 1];
        acc[0] = fmaf(va.x, w, acc[0]); acc[1] = fmaf(va.y, w, acc[1]);
        acc[2] = fmaf(va.z, w, acc[2]); acc[3] = fmaf(va.w, w, acc[3]);
        acc[4] = fmaf(vb.x, w, acc[4]); acc[5] = fmaf(vb.y, w, acc[5]);
        acc[6] = fmaf(vb.z, w, acc[6]); acc[7] = fmaf(vb.w, w, acc[7]);
    }
    if (e < DIN) {
#pragma unroll
        for (int p = 0; p < K1_PIX; p++)
            xp[((size_t)(gp0 + p)) * DIN + e] = acc[p];
    } else {
        int e2 = e - DIN;
#pragma unroll
        for (int p = 0; p < K1_PIX; p++)
            z[((size_t)(gp0 + p)) * DIN + e2] = acc[p];
    }
}

// ---------------- kernel 2: depthwise conv 3x3 + bias + SiLU ----------------
// Vectorized float4 over channels (G13): 4 pixels/block, 48 ch-groups,
// weights staged transposed in LDS.
constexpr int KC_PIX = 4;
__global__ __launch_bounds__(192) void k_conv(
        const float* __restrict__ xp, const float* __restrict__ Wc,
        const float* __restrict__ bc, float* __restrict__ xi) {
    __shared__ float sW[9][DIN];          // 6.9 KB, transposed weights
    int t = threadIdx.x;
    for (int i = t; i < DIN * 9; i += 192) {
        int d = i / 9, tap = i % 9;
        sW[tap][d] = Wc[i];
    }
    __syncthreads();
    int p   = t / 48;            // pixel within block 0..3
    int cg4 = (t % 48) * 4;      // channel quad
    int gp  = blockIdx.x * KC_PIX + p;
    int b   = gp / LL;
    int l   = gp - b * LL;
    int h   = l / WW;
    int w   = l - h * WW;
    float4 acc = *(const float4*)&bc[cg4];
#pragma unroll
    for (int dy = -1; dy <= 1; dy++) {
        int hh = h + dy;
        if (hh < 0 || hh >= HH) continue;
#pragma unroll
        for (int dx = -1; dx <= 1; dx++) {
            int ww = w + dx;
            if (ww < 0 || ww >= WW) continue;
            float4 xv = *(const float4*)&xp[((size_t)b * LL + hh * WW + ww) * DIN + cg4];
            float4 wv = *(const float4*)&sW[(dy + 1) * 3 + (dx + 1)][cg4];
            acc.x = fmaf(xv.x, wv.x, acc.x);
            acc.y = fmaf(xv.y, wv.y, acc.y);
            acc.z = fmaf(xv.z, wv.z, acc.z);
            acc.w = fmaf(xv.w, wv.w, acc.w);
        }
    }
    float4 o;
    o.x = silu(acc.x); o.y = silu(acc.y); o.z = silu(acc.z); o.w = silu(acc.w);
    *(float4*)&xi[(size_t)gp * DIN + cg4] = o;
}

// ------- kernel 3: x-proj -> dr (rank-6), B, C ------------------------------
// Weights read straight from L1/L2 (29 KB per direction, shared by all 196
// blocks of that direction; 16-lane broadcast rows).
constexpr int K3_PIX = 32;
__global__ __launch_bounds__(256) void k_xproj(
        const float* __restrict__ xi, const float* __restrict__ Wt,
        float* __restrict__ drbuf, float* __restrict__ Bbuf,
        float* __restrict__ Cbuf) {
    __shared__ float4 v4[K3_PIX][49];    // 25.1 KB
    int k   = blockIdx.y;
    int gp0 = blockIdx.x * K3_PIX;
    int b   = gp0 / LL;
    int l0  = gp0 - b * LL;
    int t   = threadIdx.x;
    const float4* xin4 = (const float4*)(xi + (size_t)gp0 * DIN);
    for (int i = t; i < K3_PIX * 48; i += 256)
        v4[i / 48][i % 48] = xin4[i];
    const float4* wt4 = (const float4*)(Wt + (size_t)k * EPROJ * DIN);
    __syncthreads();
    int p0 = t & 15;            // pixel within 16-set
    int eg = t >> 4;            // e-group 0..15
    bool has3 = (eg < EPROJ - 32);      // eg < 6
    float acc[2][3] = {{0.f, 0.f, 0.f}, {0.f, 0.f, 0.f}};
#pragma unroll 4
    for (int j = 0; j < 48; j++) {
        float4 w0 = wt4[eg * 48 + j];
        float4 w1 = wt4[(eg + 16) * 48 + j];
        float4 w2 = has3 ? wt4[(eg + 32) * 48 + j] : make_float4(0.f, 0.f, 0.f, 0.f);
#pragma unroll
        for (int q = 0; q < 2; q++) {
            float4 vv = v4[p0 + 16 * q][j];
            acc[q][0] = fmaf(vv.x, w0.x, acc[q][0]); acc[q][0] = fmaf(vv.y, w0.y, acc[q][0]);
            acc[q][0] = fmaf(vv.z, w0.z, acc[q][0]); acc[q][0] = fmaf(vv.w, w0.w, acc[q][0]);
            acc[q][1] = fmaf(vv.x, w1.x, acc[q][1]); acc[q][1] = fmaf(vv.y, w1.y, acc[q][1]);
            acc[q][1] = fmaf(vv.z, w1.z, acc[q][1]); acc[q][1] = fmaf(vv.w, w1.w, acc[q][1]);
            acc[q][2] = fmaf(vv.x, w2.x, acc[q][2]); acc[q][2] = fmaf(vv.y, w2.y, acc[q][2]);
            acc[q][2] = fmaf(vv.z, w2.z, acc[q][2]); acc[q][2] = fmaf(vv.w, w2.w, acc[q][2]);
        }
    }
#pragma unroll
    for (int q = 0; q < 2; q++) {
        int p  = p0 + 16 * q;
        int ls = spatial_to_seq(k, l0 + p);
        size_t kb  = (size_t)(k * BATCH + b);
        size_t b8  = (kb * LL + ls) * 8;
        size_t b16 = (kb * LL + ls) * NST;
        if (eg < RNK) drbuf[b8 + eg] = acc[q][0];
        else          Bbuf[b16 + eg - RNK] = acc[q][0];
        int e1 = eg + 16;
        if (e1 < RNK + NST) Bbuf[b16 + e1 - RNK] = acc[q][1];
        else                Cbuf[b16 + e1 - RNK - NST] = acc[q][1];
        if (has3) Cbuf[b16 + eg + 32 - RNK - NST] = acc[q][2];
    }
}

// -------- kernel 4a: chunk-local scan -> per-chunk summary (P, h_end) --------
// Summary stored interleaved float2 {P, h}: one coalesced 8B store here,
// one 8B load per fold iteration in k_scanC.
__global__ __launch_bounds__(256) void k_scanA(
        const float* __restrict__ xi, const float* __restrict__ drbuf,
        const float* __restrict__ Bbuf, const float* __restrict__ A_logs,
        const float* __restrict__ W_dt, const float* __restrict__ b_dt,
        float2* __restrict__ sum2) {
    __shared__ float2 sDU2[16][STDU];   // [ch][s] {delta, delta*u}
    __shared__ float  sB1t[16][STB1];   // [n][s]
    int c   = blockIdx.x;
    int blk = blockIdx.y;
    int k   = blk / (BATCH * CGRP);
    int rem = blk % (BATCH * CGRP);
    int b   = rem / CGRP;
    int cg  = rem % CGRP;
    int d0  = cg * 16;
    int t    = threadIdx.x;
    int lane = t & 63, wave = t >> 6;
    int grp  = lane >> 4, n = lane & 15;
    int ch   = wave * 4 + grp;
    int d    = d0 + ch;
    float A = -__expf(A_logs[((size_t)(k * DIN + d)) * NST + n]);
    size_t kb = (size_t)(k * BATCH + b);
    const float* drp = drbuf + kb * LL * 8;
    const float* bp  = Bbuf  + kb * LL * NST;
    const float* up  = xi    + (size_t)b * LL * DIN;
    // staging identity
    int ss  = t >> 2;            // 0..63
    int cc0 = (t & 3) * 4;       // 0,4,8,12
    float4 wr[RNK];
#pragma unroll
    for (int r = 0; r < RNK; r++)
        wr[r] = *(const float4*)(W_dt + ((size_t)k * RNK + r) * DIN + d0 + cc0);
    float4 bb4 = *(const float4*)(b_dt + k * DIN + d0 + cc0);
    int l0 = c * SCH;
    {
        int l  = l0 + ss;
        int lr = seq_to_lr(k, l);
        float4 r03 = *(const float4*)(drp + (size_t)l * 8);
        float2 r45 = *(const float2*)(drp + (size_t)l * 8 + 4);
        float4 dlt = delta4(r03, r45, wr, bb4);
        float4 u4  = *(const float4*)(up + (size_t)lr * DIN + d0 + cc0);
        float4 B4  = *(const float4*)(bp + (size_t)l * NST + cc0);
        sDU2[cc0 + 0][ss] = make_float2(dlt.x, dlt.x * u4.x);
        sDU2[cc0 + 1][ss] = make_float2(dlt.y, dlt.y * u4.y);
        sDU2[cc0 + 2][ss] = make_float2(dlt.z, dlt.z * u4.z);
        sDU2[cc0 + 3][ss] = make_float2(dlt.w, dlt.w * u4.w);
        sB1t[cc0 + 0][ss] = B4.x;
        sB1t[cc0 + 1][ss] = B4.y;
        sB1t[cc0 + 2][ss] = B4.z;
        sB1t[cc0 + 3][ss] = B4.w;
    }
    __syncthreads();
    float h = 0.0f, P = 1.0f;
#pragma unroll 2
    for (int s4 = 0; s4 < SCH; s4 += 4) {
        float4 duA = *(const float4*)&sDU2[ch][s4];
        float4 duB = *(const float4*)&sDU2[ch][s4 + 2];
        float4 bq  = *(const float4*)&sB1t[n][s4];
        float dA;
        dA = __expf(duA.x * A); h = fmaf(dA, h, duA.y * bq.x); P *= dA;
        dA = __expf(duA.z * A); h = fmaf(dA, h, duA.w * bq.y); P *= dA;
        dA = __expf(duB.x * A); h = fmaf(dA, h, duB.y * bq.z); P *= dA;
        dA = __expf(duB.z * A); h = fmaf(dA, h, duB.w * bq.w); P *= dA;
    }
    sum2[hs_idx(c, (int)kb, d, n)] = make_float2(P, h);
}

// -------- kernel 4b: chunk-local scan with inline prefix fold; emit y --------
// Fold is unrolled x8: 8 independent float2 loads per batch (one waitcnt),
// then 8 serial FMAs — cuts the per-block fold latency ~6x vs the serial
// load-load-fma chain. Fold order (ascending j) unchanged -> bit-identical.
__global__ __launch_bounds__(256) void k_scanC(
        const float* __restrict__ xi, const float* __restrict__ drbuf,
        const float* __restrict__ Bbuf, const float* __restrict__ Cbuf,
        const float* __restrict__ A_logs, const float* __restrict__ W_dt,
        const float* __restrict__ b_dt,
        const float2* __restrict__ sum2,
        float* __restrict__ ydir) {
    __shared__ float2 sDU2[16][STDU];   // [ch][s] {delta, delta*u}
    __shared__ float2 sBC2[16][STBC];   // [n][s]  {B, C}
    __shared__ float  sY[16][STY];      // [ch][s]
    int c   = blockIdx.x;
    int blk = blockIdx.y;
    int k   = blk / (BATCH * CGRP);
    int rem = blk % (BATCH * CGRP);
    int b   = rem / CGRP;
    int cg  = rem % CGRP;
    int d0  = cg * 16;
    int t    = threadIdx.x;
    int lane = t & 63, wave = t >> 6;
    int grp  = lane >> 4, n = lane & 15;
    int ch   = wave * 4 + grp;
    int d    = d0 + ch;
    float A = -__expf(A_logs[((size_t)(k * DIN + d)) * NST + n]);
    size_t kb = (size_t)(k * BATCH + b);
    const float* drp = drbuf + kb * LL * 8;
    const float* bp  = Bbuf  + kb * LL * NST;
    const float* cp  = Cbuf  + kb * LL * NST;
    const float* up  = xi    + (size_t)b * LL * DIN;
    float*       yp  = ydir  + kb * LL * DIN;     // per-direction slice
    // ---- inline prefix fold: h_in for this (d, n) over chunks 0..c-1 ----
    float hin = 0.0f;
    {
        int j = 0;
        for (; j + 8 <= c; j += 8) {
            float2 a0 = sum2[hs_idx(j + 0, (int)kb, d, n)];
            float2 a1 = sum2[hs_idx(j + 1, (int)kb, d, n)];
            float2 a2 = sum2[hs_idx(j + 2, (int)kb, d, n)];
            float2 a3 = sum2[hs_idx(j + 3, (int)kb, d, n)];
            float2 a4 = sum2[hs_idx(j + 4, (int)kb, d, n)];
            float2 a5 = sum2[hs_idx(j + 5, (int)kb, d, n)];
            float2 a6 = sum2[hs_idx(j + 6, (int)kb, d, n)];
            float2 a7 = sum2[hs_idx(j + 7, (int)kb, d, n)];
            hin = fmaf(a0.x, hin, a0.y);
            hin = fmaf(a1.x, hin, a1.y);
            hin = fmaf(a2.x, hin, a2.y);
            hin = fmaf(a3.x, hin, a3.y);
            hin = fmaf(a4.x, hin, a4.y);
            hin = fmaf(a5.x, hin, a5.y);
            hin = fmaf(a6.x, hin, a6.y);
            hin = fmaf(a7.x, hin, a7.y);
        }
        for (; j < c; j++) {
            float2 a = sum2[hs_idx(j, (int)kb, d, n)];
            hin = fmaf(a.x, hin, a.y);
        }
    }
    // ---- stage chunk data ----
    int ss  = t >> 2;
    int cc0 = (t & 3) * 4;
    float4 wr[RNK];
#pragma unroll
    for (int r = 0; r < RNK; r++)
        wr[r] = *(const float4*)(W_dt + ((size_t)k * RNK + r) * DIN + d0 + cc0);
    float4 bb4 = *(const float4*)(b_dt + k * DIN + d0 + cc0);
    int l0 = c * SCH;
    {
        int l  = l0 + ss;
        int lr = seq_to_lr(k, l);
        float4 r03 = *(const float4*)(drp + (size_t)l * 8);
        float2 r45 = *(const float2*)(drp + (size_t)l * 8 + 4);
        float4 dlt = delta4(r03, r45, wr, bb4);
        float4 u4  = *(const float4*)(up + (size_t)lr * DIN + d0 + cc0);
        float4 B4  = *(const float4*)(bp + (size_t)l * NST + cc0);
        float4 C4  = *(const float4*)(cp + (size_t)l * NST + cc0);
        sDU2[cc0 + 0][ss] = make_float2(dlt.x, dlt.x * u4.x);
        sDU2[cc0 + 1][ss] = make_float2(dlt.y, dlt.y * u4.y);
        sDU2[cc0 + 2][ss] = make_float2(dlt.z, dlt.z * u4.z);
        sDU2[cc0 + 3][ss] = make_float2(dlt.w, dlt.w * u4.w);
        sBC2[cc0 + 0][ss] = make_float2(B4.x, C4.x);
        sBC2[cc0 + 1][ss] = make_float2(B4.y, C4.y);
        sBC2[cc0 + 2][ss] = make_float2(B4.z, C4.z);
        sBC2[cc0 + 3][ss] = make_float2(B4.w, C4.w);
    }
    __syncthreads();
    float h = hin;
#pragma unroll 2
    for (int s4 = 0; s4 < SCH; s4 += 4) {
        float4 duA = *(const float4*)&sDU2[ch][s4];
        float4 duB = *(const float4*)&sDU2[ch][s4 + 2];
        float4 bcA = *(const float4*)&sBC2[n][s4];
        float4 bcB = *(const float4*)&sBC2[n][s4 + 2];
        float dA, y0, y1, y2, y3;
        dA = __expf(duA.x * A); h = fmaf(dA, h, duA.y * bcA.x); y0 = row_reduce16(h * bcA.y);
        dA = __expf(duA.z * A); h = fmaf(dA, h, duA.w * bcA.z); y1 = row_reduce16(h * bcA.w);
        dA = __expf(duB.x * A); h = fmaf(dA, h, duB.y * bcB.x); y2 = row_reduce16(h * bcB.y);
        dA = __expf(duB.z * A); h = fmaf(dA, h, duB.w * bcB.z); y3 = row_reduce16(h * bcB.w);
        if (n == 0) *(float4*)&sY[ch][s4] = make_float4(y0, y1, y2, y3);
    }
    __syncthreads();
    // vectorized writeback: one float4 store per thread (s = t>>2, quad = t&3)
    {
        int s  = t >> 2;
        int c4 = (t & 3) * 4;
        int lr = seq_to_lr(k, l0 + s);
        float4 v = make_float4(sY[c4 + 0][s], sY[c4 + 1][s],
                               sY[c4 + 2][s], sY[c4 + 3][s]);
        *(float4*)&yp[(size_t)lr * DIN + d0 + c4] = v;
    }
}

// ------- kernel 5: gather 4 directions + D*u + gate + out-projection ---------
constexpr int K5_PIX = 8;
__global__ __launch_bounds__(192) void k_out(
        const float* __restrict__ ydir, const float* __restrict__ xi,
        const float* __restrict__ zbuf, const float* __restrict__ Ds,
        const float* __restrict__ W_out, float* __restrict__ out) {
    __shared__ float g[DIN][12];           // [dd][p] padded
    __shared__ float so[CDIM][9];          // padded stores
    int gp0 = blockIdx.x * K5_PIX;
    int b   = gp0 / LL;
    int l0  = gp0 - b * LL;
    int t   = threadIdx.x;
    for (int i = t; i < K5_PIX * DIN; i += 192) {
        int p = i / DIN, dd = i % DIN;
        size_t off = (size_t)(gp0 + p) * DIN + dd;
        float y = ydir[off] + ydir[SZ_PX + off]
                + ydir[2 * SZ_PX + off] + ydir[3 * SZ_PX + off];
        float dsum = Ds[dd] + Ds[DIN + dd] + Ds[2 * DIN + dd] + Ds[3 * DIN + dd];
        y = fmaf(xi[off], dsum, y);
        g[dd][p] = y * silu(zbuf[off]);
    }
    __syncthreads();
    int f    = t % CDIM;
    int half = t / CDIM;
    float acc[4] = {0.f, 0.f, 0.f, 0.f};
#pragma unroll 4
    for (int dd = 0; dd < DIN; dd++) {
        float wv = W_out[dd * CDIM + f];
        float4 gv = *(const float4*)&g[dd][half * 4];
        acc[0] = fmaf(gv.x, wv, acc[0]);
        acc[1] = fmaf(gv.y, wv, acc[1]);
        acc[2] = fmaf(gv.z, wv, acc[2]);
        acc[3] = fmaf(gv.w, wv, acc[3]);
    }
#pragma unroll
    for (int p = 0; p < 4; p++) so[f][half * 4 + p] = acc[p];
    __syncthreads();
    for (int i = t; i < CDIM * K5_PIX; i += 192) {
        int f2 = i / K5_PIX, p2 = i % K5_PIX;
        out[((size_t)(b * CDIM + f2)) * LL + l0 + p2] = so[f2][p2];
    }
}

// ---------------- launch ----------------------------------------------------
extern "C" void kernel_launch(void* const* d_in, const int* in_sizes, int n_in,
                              void* d_out, int out_size, void* d_ws, size_t ws_size,
                              hipStream_t stream) {
    const float* x       = (const float*)d_in[0];
    const float* W_in    = (const float*)d_in[1];
    const float* W_conv  = (const float*)d_in[2];
    const float* b_conv  = (const float*)d_in[3];
    const float* W_xproj = (const float*)d_in[4];
    const float* W_dt    = (const float*)d_in[5];
    const float* b_dt    = (const float*)d_in[6];
    const float* A_logs  = (const float*)d_in[7];
    const float* Ds      = (const float*)d_in[8];
    const float* W_out   = (const float*)d_in[9];
    float* out = (float*)d_out;
    float* ws  = (float*)d_ws;

    float* xp    = ws + OFF_XP;
    float* z     = ws + OFF_Z;
    float* xi    = ws + OFF_XI;
    float* drbuf = ws + OFF_DR;
    float* Bbuf  = ws + OFF_B;
    float* Cbuf  = ws + OFF_C;
    float* ydir  = ws + OFF_YD;
    float2* sum2 = (float2*)(ws + OFF_HE);
    float* Wt    = ws + OFF_WT;

    k_inproj<<<(BATCH * LL) / K1_PIX, 384, 0, stream>>>(x, W_in, W_xproj, xp, z, Wt);
    k_conv<<<(BATCH * LL) / KC_PIX, 192, 0, stream>>>(xp, W_conv, b_conv, xi);
    dim3 g3((BATCH * LL) / K3_PIX, NK);
    k_xproj<<<g3, 256, 0, stream>>>(xi, Wt, drbuf, Bbuf, Cbuf);
    dim3 gs(NCH, NK * BATCH * CGRP);
    k_scanA<<<gs, 256, 0, stream>>>(xi, drbuf, Bbuf, A_logs, W_dt, b_dt, sum2);
    k_scanC<<<gs, 256, 0, stream>>>(xi, drbuf, Bbuf, Cbuf, A_logs, W_dt, b_dt, sum2, ydir);
    k_out<<<(BATCH * LL) / K5_PIX, 192, 0, stream>>>(ydir, xi, z, Ds, W_out, out);
}